// Round 3
// baseline (1913.410 us; speedup 1.0000x reference)
//
#include <hip/hip_runtime.h>
#include <hip/hip_bf16.h>

#define B_ 2
#define L_ 4096
#define D_ 1024
#define H_ 16
#define DK_ 64
#define R_ (B_*L_)   // 8192 tokens

__device__ __forceinline__ float wave_sum(float v) {
    #pragma unroll
    for (int off = 32; off > 0; off >>= 1) v += __shfl_xor(v, off, 64);
    return v;
}

__device__ __forceinline__ void load4f(const float* p, float f[4]) {
    const float4 v = *reinterpret_cast<const float4*>(p);
    f[0] = v.x; f[1] = v.y; f[2] = v.z; f[3] = v.w;
}

// ---------------------------------------------------------------------------
// Tiled GEMM: C[M,N] = A[M,K] @ B[K,N], all fp32. 64x64 tile, BK=16, 256 thr,
// 4x4 microtile.
// ---------------------------------------------------------------------------
__global__ __launch_bounds__(256) void gemm_kernel(
    const float* __restrict__ A, const float* __restrict__ Bw,
    float* __restrict__ C, int M, int N, int K)
{
    constexpr int BK = 16;
    __shared__ float As[BK][64 + 1];
    __shared__ float Bs[BK][64 + 1];
    const int bm = blockIdx.y * 64;
    const int bn = blockIdx.x * 64;
    const int t  = threadIdx.x;
    const int tx = t & 15, ty = t >> 4;
    const int am  = t >> 2;          // A tile row this thread loads
    const int ak  = (t & 3) * 4;     // A tile k-offset (4 contiguous)
    const int bk  = t >> 4;          // B tile k-row
    const int bn4 = (t & 15) * 4;    // B tile n-offset (4 contiguous)
    float acc[4][4] = {};
    for (int k0 = 0; k0 < K; k0 += BK) {
        float av[4], bv[4];
        load4f(A  + (size_t)(bm + am) * K + k0 + ak, av);
        load4f(Bw + (size_t)(k0 + bk) * N + bn + bn4, bv);
        #pragma unroll
        for (int u = 0; u < 4; ++u) As[ak + u][am] = av[u];
        #pragma unroll
        for (int u = 0; u < 4; ++u) Bs[bk][bn4 + u] = bv[u];
        __syncthreads();
        #pragma unroll
        for (int kk = 0; kk < BK; ++kk) {
            float a[4], b[4];
            #pragma unroll
            for (int i = 0; i < 4; ++i) a[i] = As[kk][ty * 4 + i];
            #pragma unroll
            for (int j = 0; j < 4; ++j) b[j] = Bs[kk][tx * 4 + j];
            #pragma unroll
            for (int i = 0; i < 4; ++i)
                #pragma unroll
                for (int j = 0; j < 4; ++j)
                    acc[i][j] = fmaf(a[i], b[j], acc[i][j]);
        }
        __syncthreads();
    }
    #pragma unroll
    for (int i = 0; i < 4; ++i) {
        size_t row = (size_t)(bm + ty * 4 + i) * N + bn + tx * 4;
        #pragma unroll
        for (int j = 0; j < 4; ++j) C[row + j] = acc[i][j];
    }
}

// ---------------------------------------------------------------------------
// Small projections: beta = sig(x@Wb), fast = sig(x@Wfd+bfd), slow = sig(x@Wsd+bsd)
// One block per token, 64 threads; lanes 0..47 each own one output column.
// Output layout [bh][l].
// ---------------------------------------------------------------------------
__global__ __launch_bounds__(64) void small_proj_kernel(
    const float* __restrict__ x,
    const float* __restrict__ Wb, const float* __restrict__ Wfd,
    const float* __restrict__ bfd, const float* __restrict__ Wsd,
    const float* __restrict__ bsd,
    float* __restrict__ beta, float* __restrict__ fastd, float* __restrict__ slowd)
{
    __shared__ float xs[D_];
    const int r = blockIdx.x;
    for (int i = threadIdx.x; i < D_; i += 64) xs[i] = x[(size_t)r * D_ + i];
    __syncthreads();
    const int t = threadIdx.x;
    if (t < 48) {
        const int which = t >> 4, c = t & 15;
        const float* W = which == 0 ? Wb : (which == 1 ? Wfd : Wsd);
        float acc = 0.f;
        for (int i = 0; i < D_; ++i) acc = fmaf(xs[i], W[i * H_ + c], acc);
        if (which == 1) acc += bfd[c];
        if (which == 2) acc += bsd[c];
        const float sg = 1.f / (1.f + expf(-acc));
        const int b = r >> 12, l = r & (L_ - 1);
        float* dst = which == 0 ? beta : (which == 1 ? fastd : slowd);
        dst[(size_t)(b * H_ + c) * L_ + l] = sg;
    }
}

// ---------------------------------------------------------------------------
// Per-(b,h) inclusive scan of log(decay+1e-6); w = exp(total - cs); denom = sum(w)+1e-6.
// One block per (bh, fast/slow); 256 threads x 16 elements.
// ---------------------------------------------------------------------------
__global__ __launch_bounds__(256) void scan_kernel(
    const float* __restrict__ fastd, const float* __restrict__ slowd,
    float* __restrict__ fw, float* __restrict__ sw, float* __restrict__ denom)
{
    __shared__ float part[256];
    const int bh = blockIdx.x >> 1;
    const int which = blockIdx.x & 1;
    const float* src = (which ? slowd : fastd) + (size_t)bh * L_;
    float* dst = (which ? sw : fw) + (size_t)bh * L_;
    const int t = threadIdx.x;
    float vals[16];
    float run = 0.f;
    #pragma unroll
    for (int i = 0; i < 16; ++i) {
        run += logf(src[t * 16 + i] + 1e-6f);
        vals[i] = run;
    }
    part[t] = run;
    __syncthreads();
    for (int off = 1; off < 256; off <<= 1) {
        float v = (t >= off) ? part[t - off] : 0.f;
        __syncthreads();
        part[t] += v;
        __syncthreads();
    }
    const float excl = part[t] - run;
    const float total = part[255];
    __syncthreads();
    float lsum = 0.f;
    #pragma unroll
    for (int i = 0; i < 16; ++i) {
        float w = expf(total - (vals[i] + excl));
        dst[t * 16 + i] = w;
        lsum += w;
    }
    part[t] = lsum;
    __syncthreads();
    for (int off = 128; off > 0; off >>= 1) {
        if (t < off) part[t] += part[t + off];
        __syncthreads();
    }
    if (t == 0) denom[bh * 2 + which] = part[0] + 1e-6f;
}

// ---------------------------------------------------------------------------
// Per-(token,head) wave: l2norm q,k; k_beta, v_scaled (in place); token-flux MLP -> alpha.
// 4 waves/block, one (token,head) per wave, lane = dk element.
// ---------------------------------------------------------------------------
__global__ __launch_bounds__(256) void normflux_kernel(
    float* __restrict__ Q, float* __restrict__ Kb, float* __restrict__ Vb,
    const float* __restrict__ beta,
    const float* __restrict__ Wtf1, const float* __restrict__ btf1,
    const float* __restrict__ Wtf2, const float* __restrict__ btf2,
    float* __restrict__ alphaA)
{
    __shared__ float kbs[4][64];
    const int wv = threadIdx.x >> 6;
    const int lane = threadIdx.x & 63;
    const int w = blockIdx.x * 4 + wv;
    const int r = w >> 4;           // token index (b*L + l)
    const int h = w & 15;
    const int b = r >> 12;
    const int l = r & (L_ - 1);
    const int bh = b * H_ + h;
    const size_t idx = (size_t)r * D_ + h * DK_ + lane;
    const float qv = Q[idx], kv = Kb[idx], vv = Vb[idx];
    const float qs = wave_sum(qv * qv);
    const float ks = wave_sum(kv * kv);
    const float qn = qv / fmaxf(sqrtf(qs), 1e-12f);
    const float kn = kv / fmaxf(sqrtf(ks), 1e-12f);
    const float bt = beta[(size_t)bh * L_ + l];
    const float kb = kn * bt;
    Q[idx] = qn; Kb[idx] = kb; Vb[idx] = vv * bt;
    kbs[wv][lane] = kb;
    __syncthreads();
    float hm = 0.f;
    if (lane < 32) {
        float acc = btf1[lane];
        #pragma unroll 8
        for (int i = 0; i < 64; ++i)
            acc = fmaf(kbs[wv][i], Wtf1[i * 32 + lane], acc);
        const float sg = 1.f / (1.f + expf(-acc));
        hm = acc * sg * Wtf2[lane];            // fold Wtf2 column into reduce
    }
    const float tfs = wave_sum(hm);
    float tf = 1.f / (1.f + expf(-(tfs + btf2[0])));
    tf = fminf(fmaxf(tf, 0.01f), 0.99f);
    if (lane == 0) alphaA[(size_t)bh * L_ + l] = 0.5f + 0.3f * tf;
}

// ---------------------------------------------------------------------------
// M_fast/M_slow: per (bh, L-segment) partial outer-product sums, atomicAdd into M.
// Thread owns (d, 16 e's); LDS-staged 32-l chunks.
// ---------------------------------------------------------------------------
__global__ __launch_bounds__(256) void mstate_kernel(
    const float* __restrict__ Kb, const float* __restrict__ Vb,
    const float* __restrict__ fw, const float* __restrict__ sw,
    float* __restrict__ Mf, float* __restrict__ Ms)
{
    __shared__ float ks[32][64];
    __shared__ float vs[32][64];
    __shared__ float wfl[32], wsl[32];
    const int bh = blockIdx.x;
    const int b = bh >> 4, h = bh & 15;
    const int t = threadIdx.x;
    const int d = t >> 2;
    const int e0 = (t & 3) * 16;
    float accF[16] = {}, accS[16] = {};
    const int l0base = blockIdx.y * (L_ / 8);
    for (int l0 = l0base; l0 < l0base + L_ / 8; l0 += 32) {
        #pragma unroll
        for (int rep = 0; rep < 8; ++rep) {
            const int idx = t + rep * 256;
            const int ll = idx >> 6, e = idx & 63;
            const size_t g = (size_t)(b * L_ + l0 + ll) * D_ + h * DK_ + e;
            ks[ll][e] = Kb[g];
            vs[ll][e] = Vb[g];
        }
        if (t < 32) {
            wfl[t] = fw[(size_t)bh * L_ + l0 + t];
            wsl[t] = sw[(size_t)bh * L_ + l0 + t];
        }
        __syncthreads();
        #pragma unroll 4
        for (int ll = 0; ll < 32; ++ll) {
            const float kf  = ks[ll][d] * wfl[ll];
            const float ksl = ks[ll][d] * wsl[ll];
            #pragma unroll
            for (int j = 0; j < 16; ++j) {
                const float vv = vs[ll][e0 + j];
                accF[j] = fmaf(kf,  vv, accF[j]);
                accS[j] = fmaf(ksl, vv, accS[j]);
            }
        }
        __syncthreads();
    }
    #pragma unroll
    for (int j = 0; j < 16; ++j) {
        atomicAdd(&Mf[(size_t)bh * (DK_ * DK_) + d * DK_ + e0 + j], accF[j]);
        atomicAdd(&Ms[(size_t)bh * (DK_ * DK_) + d * DK_ + e0 + j], accS[j]);
    }
}

// ---------------------------------------------------------------------------
// o = alpha*(q@Mf)/dF + (1-alpha)*(q@Ms)/dS.  M tiles in LDS, wave per token.
// ---------------------------------------------------------------------------
__global__ __launch_bounds__(256) void o_kernel(
    const float* __restrict__ Q, const float* __restrict__ Mf, const float* __restrict__ Ms,
    const float* __restrict__ alphaA, const float* __restrict__ denom,
    float* __restrict__ Oo)
{
    __shared__ float Mfs[DK_ * DK_];
    __shared__ float Mss[DK_ * DK_];
    const int bh = blockIdx.x;
    const int b = bh >> 4, h = bh & 15;
    for (int i = threadIdx.x; i < DK_ * DK_; i += 256) {
        Mfs[i] = Mf[(size_t)bh * (DK_ * DK_) + i];
        Mss[i] = Ms[(size_t)bh * (DK_ * DK_) + i];
    }
    __syncthreads();
    const float dF = denom[bh * 2 + 0], dS = denom[bh * 2 + 1];
    const int wv = threadIdx.x >> 6, lane = threadIdx.x & 63;
    for (int it = 0; it < 8; ++it) {
        const int l = blockIdx.y * 32 + wv * 8 + it;
        const size_t idx = (size_t)(b * L_ + l) * D_ + h * DK_ + lane;
        const float qv = Q[idx];
        float of = 0.f, os = 0.f;
        #pragma unroll 16
        for (int d = 0; d < 64; ++d) {
            const float qd = __shfl(qv, d, 64);
            of = fmaf(qd, Mfs[d * 64 + lane], of);
            os = fmaf(qd, Mss[d * 64 + lane], os);
        }
        const float a = alphaA[(size_t)bh * L_ + l];
        Oo[idx] = a * (of / dF) + (1.f - a) * (os / dS);
    }
}

extern "C" void kernel_launch(void* const* d_in, const int* in_sizes, int n_in,
                              void* d_out, int out_size, void* d_ws, size_t ws_size,
                              hipStream_t stream)
{
    const float* x    = (const float*)d_in[0];
    const float* Wq   = (const float*)d_in[1];
    const float* Wk   = (const float*)d_in[2];
    const float* Wv   = (const float*)d_in[3];
    const float* Wb   = (const float*)d_in[4];
    const float* Wo   = (const float*)d_in[5];
    const float* Wfd  = (const float*)d_in[6];
    const float* bfd  = (const float*)d_in[7];
    const float* Wsd  = (const float*)d_in[8];
    const float* bsd  = (const float*)d_in[9];
    const float* Wtf1 = (const float*)d_in[10];
    const float* btf1 = (const float*)d_in[11];
    const float* Wtf2 = (const float*)d_in[12];
    const float* btf2 = (const float*)d_in[13];
    float* out        = (float*)d_out;

    float* ws     = (float*)d_ws;
    float* Q      = ws;                    // [8192,1024] fp32
    float* Kb     = Q  + (size_t)R_ * D_;  // k_beta, later reused as o
    float* Vb     = Kb + (size_t)R_ * D_;  // v_scaled
    float* beta   = Vb + (size_t)R_ * D_;  // [32][4096]
    float* fastd  = beta  + 32 * L_;
    float* slowd  = fastd + 32 * L_;
    float* fw     = slowd + 32 * L_;
    float* sw     = fw    + 32 * L_;
    float* alphaA = sw    + 32 * L_;
    float* Mf     = alphaA + 32 * L_;      // [32][64][64]
    float* Ms     = Mf + 32 * DK_ * DK_;
    float* denom  = Ms + 32 * DK_ * DK_;   // [32][2]

    small_proj_kernel<<<R_, 64, 0, stream>>>(x, Wb, Wfd, bfd, Wsd, bsd, beta, fastd, slowd);
    gemm_kernel<<<dim3(16, 128), 256, 0, stream>>>(x, Wq, Q,  R_, D_, D_);
    gemm_kernel<<<dim3(16, 128), 256, 0, stream>>>(x, Wk, Kb, R_, D_, D_);
    gemm_kernel<<<dim3(16, 128), 256, 0, stream>>>(x, Wv, Vb, R_, D_, D_);
    scan_kernel<<<64, 256, 0, stream>>>(fastd, slowd, fw, sw, denom);
    normflux_kernel<<<R_ * H_ / 4, 256, 0, stream>>>(Q, Kb, Vb, beta, Wtf1, btf1, Wtf2, btf2, alphaA);
    (void)hipMemsetAsync(Mf, 0, 2 * 32 * DK_ * DK_ * sizeof(float), stream);
    mstate_kernel<<<dim3(32, 8), 256, 0, stream>>>(Kb, Vb, fw, sw, Mf, Ms);
    o_kernel<<<dim3(32, 128), 256, 0, stream>>>(Q, Mf, Ms, alphaA, denom, Kb);
    gemm_kernel<<<dim3(16, 128), 256, 0, stream>>>(Kb, Wo, out, R_, D_, D_);
}

// Round 4
// 769.156 us; speedup vs baseline: 2.4877x; 2.4877x over previous
//
#include <hip/hip_runtime.h>
#include <hip/hip_bf16.h>

#define B_ 2
#define L_ 4096
#define D_ 1024
#define H_ 16
#define DK_ 64
#define R_ (B_*L_)   // 8192 tokens

typedef __bf16 bf16x8 __attribute__((ext_vector_type(8)));
typedef float  f32x4  __attribute__((ext_vector_type(4)));

__device__ __forceinline__ float wave_sum(float v) {
    #pragma unroll
    for (int off = 32; off > 0; off >>= 1) v += __shfl_xor(v, off, 64);
    return v;
}

__device__ __forceinline__ unsigned short f2bf(float f) {   // RNE
    unsigned int u = __float_as_uint(f);
    return (unsigned short)((u + 0x7fffu + ((u >> 16) & 1u)) >> 16);
}

// async global->LDS, 16 B per lane; LDS dest = wave-uniform base + lane*16
__device__ __forceinline__ void gl_lds16(const void* g, void* l) {
    __builtin_amdgcn_global_load_lds(
        (const __attribute__((address_space(1))) void*)(uintptr_t)g,
        (__attribute__((address_space(3))) void*)(unsigned int)(uintptr_t)l,
        16, 0, 0);
}

// ---------------------------------------------------------------------------
// fp32 -> bf16 elementwise (vec4)
// ---------------------------------------------------------------------------
__global__ __launch_bounds__(256) void cvt_bf16_kernel(
    const float* __restrict__ src, unsigned short* __restrict__ dst, int n4)
{
    int i = blockIdx.x * 256 + threadIdx.x;
    if (i < n4) {
        float4 v = ((const float4*)src)[i];
        ushort4 o;
        o.x = f2bf(v.x); o.y = f2bf(v.y); o.z = f2bf(v.z); o.w = f2bf(v.w);
        ((ushort4*)dst)[i] = o;
    }
}

// ---------------------------------------------------------------------------
// fp32 W[K=1024][N=1024] -> bf16 Wt[N][K] (transpose + downcast), 32x32 tiles
// ---------------------------------------------------------------------------
__global__ __launch_bounds__(256) void transpose_bf16_kernel(
    const float* __restrict__ W, unsigned short* __restrict__ Wt)
{
    __shared__ unsigned short tile[32][33];
    const int bn = blockIdx.x * 32;   // n (col of W, row of Wt)
    const int bk = blockIdx.y * 32;   // k (row of W, col of Wt)
    const int tx = threadIdx.x & 31, ty = threadIdx.x >> 5;
    #pragma unroll
    for (int r = ty; r < 32; r += 8)
        tile[tx][r] = f2bf(W[(size_t)(bk + r) * D_ + bn + tx]);
    __syncthreads();
    #pragma unroll
    for (int r = ty; r < 32; r += 8)
        Wt[(size_t)(bn + r) * D_ + bk + tx] = tile[r][tx];
}

// ---------------------------------------------------------------------------
// bf16 MFMA GEMM (m97 structure): C[M,N] = A[M,K] @ Bt[N,K]^T, C fp32.
// 128x128 tile, BK=32, 256 thr (4 waves, 2x2), 4x4 16x16 frags per wave.
// ---------------------------------------------------------------------------
__global__ __launch_bounds__(256) void gemm_bf16_kernel(
    const unsigned short* __restrict__ A,   // [M,K] bf16 bits
    const unsigned short* __restrict__ Bt,  // [N,K] bf16 bits
    float* __restrict__ C, int M, int N, int K)
{
    __shared__ unsigned short As[128 * 32];
    __shared__ unsigned short Bs[128 * 32];
    const int bm = blockIdx.y * 128;
    const int bn = blockIdx.x * 128;
    const int t = threadIdx.x;
    const int wv = t >> 6, lane = t & 63;
    const int q  = lane >> 4, ml = lane & 15;
    const int wm = (wv >> 1) * 64, wn = (wv & 1) * 64;
    const int row4 = t >> 2;            // 0..63
    const int kof  = (t & 3) * 8;       // 0,8,16,24
    f32x4 acc[4][4] = {};
    for (int k0 = 0; k0 < K; k0 += 32) {
        __syncthreads();
        #pragma unroll
        for (int i = 0; i < 2; ++i) {
            const unsigned short* ga = A  + (size_t)(bm + i * 64 + row4) * K + k0 + kof;
            const unsigned short* gb = Bt + (size_t)(bn + i * 64 + row4) * K + k0 + kof;
            gl_lds16(ga, &As[(i * 256 + wv * 64) * 8]);
            gl_lds16(gb, &Bs[(i * 256 + wv * 64) * 8]);
        }
        __syncthreads();
        bf16x8 af[4], bfr[4];
        #pragma unroll
        for (int i = 0; i < 4; ++i)
            af[i] = *(const bf16x8*)&As[(wm + i * 16 + ml) * 32 + q * 8];
        #pragma unroll
        for (int j = 0; j < 4; ++j)
            bfr[j] = *(const bf16x8*)&Bs[(wn + j * 16 + ml) * 32 + q * 8];
        #pragma unroll
        for (int i = 0; i < 4; ++i)
            #pragma unroll
            for (int j = 0; j < 4; ++j)
                acc[i][j] = __builtin_amdgcn_mfma_f32_16x16x32_bf16(af[i], bfr[j], acc[i][j], 0, 0, 0);
    }
    // C/D layout: col = lane&15, row = (lane>>4)*4 + reg  [m89/m91 verified]
    #pragma unroll
    for (int i = 0; i < 4; ++i) {
        #pragma unroll
        for (int r = 0; r < 4; ++r) {
            const int row = bm + wm + i * 16 + q * 4 + r;
            float* cp = C + (size_t)row * N + bn + wn + ml;
            #pragma unroll
            for (int j = 0; j < 4; ++j)
                cp[j * 16] = acc[i][j][r];
        }
    }
}

// ---------------------------------------------------------------------------
// Small projections: beta = sig(x@Wb), fast = sig(x@Wfd+bfd), slow = sig(x@Wsd+bsd)
// ---------------------------------------------------------------------------
__global__ __launch_bounds__(64) void small_proj_kernel(
    const float* __restrict__ x,
    const float* __restrict__ Wb, const float* __restrict__ Wfd,
    const float* __restrict__ bfd, const float* __restrict__ Wsd,
    const float* __restrict__ bsd,
    float* __restrict__ beta, float* __restrict__ fastd, float* __restrict__ slowd)
{
    __shared__ float xs[D_];
    const int r = blockIdx.x;
    for (int i = threadIdx.x; i < D_; i += 64) xs[i] = x[(size_t)r * D_ + i];
    __syncthreads();
    const int t = threadIdx.x;
    if (t < 48) {
        const int which = t >> 4, c = t & 15;
        const float* W = which == 0 ? Wb : (which == 1 ? Wfd : Wsd);
        float acc = 0.f;
        for (int i = 0; i < D_; ++i) acc = fmaf(xs[i], W[i * H_ + c], acc);
        if (which == 1) acc += bfd[c];
        if (which == 2) acc += bsd[c];
        const float sg = 1.f / (1.f + expf(-acc));
        const int b = r >> 12, l = r & (L_ - 1);
        float* dst = which == 0 ? beta : (which == 1 ? fastd : slowd);
        dst[(size_t)(b * H_ + c) * L_ + l] = sg;
    }
}

// ---------------------------------------------------------------------------
// Per-(b,h) scan of log(decay+1e-6); w = exp(total - cs); denom = sum(w)+1e-6.
// ---------------------------------------------------------------------------
__global__ __launch_bounds__(256) void scan_kernel(
    const float* __restrict__ fastd, const float* __restrict__ slowd,
    float* __restrict__ fw, float* __restrict__ sw, float* __restrict__ denom)
{
    __shared__ float part[256];
    const int bh = blockIdx.x >> 1;
    const int which = blockIdx.x & 1;
    const float* src = (which ? slowd : fastd) + (size_t)bh * L_;
    float* dst = (which ? sw : fw) + (size_t)bh * L_;
    const int t = threadIdx.x;
    float vals[16];
    float run = 0.f;
    #pragma unroll
    for (int i = 0; i < 16; ++i) {
        run += logf(src[t * 16 + i] + 1e-6f);
        vals[i] = run;
    }
    part[t] = run;
    __syncthreads();
    for (int off = 1; off < 256; off <<= 1) {
        float v = (t >= off) ? part[t - off] : 0.f;
        __syncthreads();
        part[t] += v;
        __syncthreads();
    }
    const float excl = part[t] - run;
    const float total = part[255];
    __syncthreads();
    float lsum = 0.f;
    #pragma unroll
    for (int i = 0; i < 16; ++i) {
        float w = expf(total - (vals[i] + excl));
        dst[t * 16 + i] = w;
        lsum += w;
    }
    part[t] = lsum;
    __syncthreads();
    for (int off = 128; off > 0; off >>= 1) {
        if (t < off) part[t] += part[t + off];
        __syncthreads();
    }
    if (t == 0) denom[bh * 2 + which] = part[0] + 1e-6f;
}

// ---------------------------------------------------------------------------
// Per-(token,head) wave: l2norm q,k; k_beta, v_scaled; token-flux MLP -> alpha.
// ---------------------------------------------------------------------------
__global__ __launch_bounds__(256) void normflux_kernel(
    float* __restrict__ Q, float* __restrict__ Kb, float* __restrict__ Vb,
    const float* __restrict__ beta,
    const float* __restrict__ Wtf1, const float* __restrict__ btf1,
    const float* __restrict__ Wtf2, const float* __restrict__ btf2,
    float* __restrict__ alphaA)
{
    __shared__ float kbs[4][64];
    const int wv = threadIdx.x >> 6;
    const int lane = threadIdx.x & 63;
    const int w = blockIdx.x * 4 + wv;
    const int r = w >> 4;
    const int h = w & 15;
    const int b = r >> 12;
    const int l = r & (L_ - 1);
    const int bh = b * H_ + h;
    const size_t idx = (size_t)r * D_ + h * DK_ + lane;
    const float qv = Q[idx], kv = Kb[idx], vv = Vb[idx];
    const float qs = wave_sum(qv * qv);
    const float ks = wave_sum(kv * kv);
    const float qn = qv / fmaxf(sqrtf(qs), 1e-12f);
    const float kn = kv / fmaxf(sqrtf(ks), 1e-12f);
    const float bt = beta[(size_t)bh * L_ + l];
    const float kb = kn * bt;
    Q[idx] = qn; Kb[idx] = kb; Vb[idx] = vv * bt;
    kbs[wv][lane] = kb;
    __syncthreads();
    float hm = 0.f;
    if (lane < 32) {
        float acc = btf1[lane];
        #pragma unroll 8
        for (int i = 0; i < 64; ++i)
            acc = fmaf(kbs[wv][i], Wtf1[i * 32 + lane], acc);
        const float sg = 1.f / (1.f + expf(-acc));
        hm = acc * sg * Wtf2[lane];
    }
    const float tfs = wave_sum(hm);
    float tf = 1.f / (1.f + expf(-(tfs + btf2[0])));
    tf = fminf(fmaxf(tf, 0.01f), 0.99f);
    if (lane == 0) alphaA[(size_t)bh * L_ + l] = 0.5f + 0.3f * tf;
}

// ---------------------------------------------------------------------------
// M_fast/M_slow partial outer-product sums, atomicAdd into M.
// ---------------------------------------------------------------------------
__global__ __launch_bounds__(256) void mstate_kernel(
    const float* __restrict__ Kb, const float* __restrict__ Vb,
    const float* __restrict__ fw, const float* __restrict__ sw,
    float* __restrict__ Mf, float* __restrict__ Ms)
{
    __shared__ float ks[32][64];
    __shared__ float vs[32][64];
    __shared__ float wfl[32], wsl[32];
    const int bh = blockIdx.x;
    const int b = bh >> 4, h = bh & 15;
    const int t = threadIdx.x;
    const int d = t >> 2;
    const int e0 = (t & 3) * 16;
    float accF[16] = {}, accS[16] = {};
    const int l0base = blockIdx.y * (L_ / 8);
    for (int l0 = l0base; l0 < l0base + L_ / 8; l0 += 32) {
        #pragma unroll
        for (int rep = 0; rep < 8; ++rep) {
            const int idx = t + rep * 256;
            const int ll = idx >> 6, e = idx & 63;
            const size_t g = (size_t)(b * L_ + l0 + ll) * D_ + h * DK_ + e;
            ks[ll][e] = Kb[g];
            vs[ll][e] = Vb[g];
        }
        if (t < 32) {
            wfl[t] = fw[(size_t)bh * L_ + l0 + t];
            wsl[t] = sw[(size_t)bh * L_ + l0 + t];
        }
        __syncthreads();
        #pragma unroll 4
        for (int ll = 0; ll < 32; ++ll) {
            const float kf  = ks[ll][d] * wfl[ll];
            const float ksl = ks[ll][d] * wsl[ll];
            #pragma unroll
            for (int j = 0; j < 16; ++j) {
                const float vv = vs[ll][e0 + j];
                accF[j] = fmaf(kf,  vv, accF[j]);
                accS[j] = fmaf(ksl, vv, accS[j]);
            }
        }
        __syncthreads();
    }
    #pragma unroll
    for (int j = 0; j < 16; ++j) {
        atomicAdd(&Mf[(size_t)bh * (DK_ * DK_) + d * DK_ + e0 + j], accF[j]);
        atomicAdd(&Ms[(size_t)bh * (DK_ * DK_) + d * DK_ + e0 + j], accS[j]);
    }
}

// ---------------------------------------------------------------------------
// o = alpha*(q@Mf)/dF + (1-alpha)*(q@Ms)/dS, written as bf16 for final GEMM.
// ---------------------------------------------------------------------------
__global__ __launch_bounds__(256) void o_kernel(
    const float* __restrict__ Q, const float* __restrict__ Mf, const float* __restrict__ Ms,
    const float* __restrict__ alphaA, const float* __restrict__ denom,
    unsigned short* __restrict__ Ob)
{
    __shared__ float Mfs[DK_ * DK_];
    __shared__ float Mss[DK_ * DK_];
    const int bh = blockIdx.x;
    const int b = bh >> 4, h = bh & 15;
    for (int i = threadIdx.x; i < DK_ * DK_; i += 256) {
        Mfs[i] = Mf[(size_t)bh * (DK_ * DK_) + i];
        Mss[i] = Ms[(size_t)bh * (DK_ * DK_) + i];
    }
    __syncthreads();
    const float dF = denom[bh * 2 + 0], dS = denom[bh * 2 + 1];
    const int wv = threadIdx.x >> 6, lane = threadIdx.x & 63;
    for (int it = 0; it < 8; ++it) {
        const int l = blockIdx.y * 32 + wv * 8 + it;
        const size_t idx = (size_t)(b * L_ + l) * D_ + h * DK_ + lane;
        const float qv = Q[idx];
        float of = 0.f, os = 0.f;
        #pragma unroll 16
        for (int d = 0; d < 64; ++d) {
            const float qd = __shfl(qv, d, 64);
            of = fmaf(qd, Mfs[d * 64 + lane], of);
            os = fmaf(qd, Mss[d * 64 + lane], os);
        }
        const float a = alphaA[(size_t)bh * L_ + l];
        Ob[idx] = f2bf(a * (of / dF) + (1.f - a) * (os / dS));
    }
}

extern "C" void kernel_launch(void* const* d_in, const int* in_sizes, int n_in,
                              void* d_out, int out_size, void* d_ws, size_t ws_size,
                              hipStream_t stream)
{
    const float* x    = (const float*)d_in[0];
    const float* Wq   = (const float*)d_in[1];
    const float* Wk   = (const float*)d_in[2];
    const float* Wv   = (const float*)d_in[3];
    const float* Wb   = (const float*)d_in[4];
    const float* Wo   = (const float*)d_in[5];
    const float* Wfd  = (const float*)d_in[6];
    const float* bfd  = (const float*)d_in[7];
    const float* Wsd  = (const float*)d_in[8];
    const float* bsd  = (const float*)d_in[9];
    const float* Wtf1 = (const float*)d_in[10];
    const float* btf1 = (const float*)d_in[11];
    const float* Wtf2 = (const float*)d_in[12];
    const float* btf2 = (const float*)d_in[13];
    float* out        = (float*)d_out;

    char* w = (char*)d_ws;
    float* Q   = (float*)w;  w += (size_t)R_ * D_ * 4;
    float* Kb  = (float*)w;  w += (size_t)R_ * D_ * 4;
    float* Vb  = (float*)w;  w += (size_t)R_ * D_ * 4;
    unsigned short* xb  = (unsigned short*)w; w += (size_t)R_ * D_ * 2;  // reused as Ob
    unsigned short* Wtq = (unsigned short*)w; w += (size_t)D_ * D_ * 2;
    unsigned short* Wtk = (unsigned short*)w; w += (size_t)D_ * D_ * 2;
    unsigned short* Wtv = (unsigned short*)w; w += (size_t)D_ * D_ * 2;
    unsigned short* Wto = (unsigned short*)w; w += (size_t)D_ * D_ * 2;
    float* beta   = (float*)w; w += 32 * L_ * 4;
    float* fastd  = (float*)w; w += 32 * L_ * 4;
    float* slowd  = (float*)w; w += 32 * L_ * 4;
    float* fw     = (float*)w; w += 32 * L_ * 4;
    float* sw     = (float*)w; w += 32 * L_ * 4;
    float* alphaA = (float*)w; w += 32 * L_ * 4;
    float* Mf     = (float*)w; w += 32 * DK_ * DK_ * 4;
    float* Ms     = (float*)w; w += 32 * DK_ * DK_ * 4;
    float* denom  = (float*)w; w += 64 * 4;

    // bf16 conversions
    cvt_bf16_kernel<<<(R_ * D_ / 4 + 255) / 256, 256, 0, stream>>>(x, xb, R_ * D_ / 4);
    transpose_bf16_kernel<<<dim3(32, 32), 256, 0, stream>>>(Wq, Wtq);
    transpose_bf16_kernel<<<dim3(32, 32), 256, 0, stream>>>(Wk, Wtk);
    transpose_bf16_kernel<<<dim3(32, 32), 256, 0, stream>>>(Wv, Wtv);
    transpose_bf16_kernel<<<dim3(32, 32), 256, 0, stream>>>(Wo, Wto);

    small_proj_kernel<<<R_, 64, 0, stream>>>(x, Wb, Wfd, bfd, Wsd, bsd, beta, fastd, slowd);
    gemm_bf16_kernel<<<dim3(D_ / 128, R_ / 128), 256, 0, stream>>>(xb, Wtq, Q,  R_, D_, D_);
    gemm_bf16_kernel<<<dim3(D_ / 128, R_ / 128), 256, 0, stream>>>(xb, Wtk, Kb, R_, D_, D_);
    gemm_bf16_kernel<<<dim3(D_ / 128, R_ / 128), 256, 0, stream>>>(xb, Wtv, Vb, R_, D_, D_);
    scan_kernel<<<64, 256, 0, stream>>>(fastd, slowd, fw, sw, denom);
    normflux_kernel<<<R_ * H_ / 4, 256, 0, stream>>>(Q, Kb, Vb, beta, Wtf1, btf1, Wtf2, btf2, alphaA);
    (void)hipMemsetAsync(Mf, 0, 2 * 32 * DK_ * DK_ * sizeof(float), stream);
    mstate_kernel<<<dim3(32, 8), 256, 0, stream>>>(Kb, Vb, fw, sw, Mf, Ms);
    o_kernel<<<dim3(32, 128), 256, 0, stream>>>(Q, Mf, Ms, alphaA, denom, xb);
    gemm_bf16_kernel<<<dim3(D_ / 128, R_ / 128), 256, 0, stream>>>(xb, Wto, out, R_, D_, D_);
}

// Round 5
// 553.995 us; speedup vs baseline: 3.4538x; 1.3884x over previous
//
#include <hip/hip_runtime.h>
#include <hip/hip_bf16.h>

#define B_ 2
#define L_ 4096
#define D_ 1024
#define H_ 16
#define DK_ 64
#define R_ (B_*L_)   // 8192 tokens

typedef __bf16 bf16x8 __attribute__((ext_vector_type(8)));
typedef float  f32x4  __attribute__((ext_vector_type(4)));

__device__ __forceinline__ float wave_sum(float v) {
    #pragma unroll
    for (int off = 32; off > 0; off >>= 1) v += __shfl_xor(v, off, 64);
    return v;
}

__device__ __forceinline__ unsigned short f2bf(float f) {   // RNE
    unsigned int u = __float_as_uint(f);
    return (unsigned short)((u + 0x7fffu + ((u >> 16) & 1u)) >> 16);
}

// async global->LDS, 16 B per lane; LDS dest = wave-uniform base + lane*16
__device__ __forceinline__ void gl_lds16(const void* g, void* l) {
    __builtin_amdgcn_global_load_lds(
        (const __attribute__((address_space(1))) void*)(uintptr_t)g,
        (__attribute__((address_space(3))) void*)(unsigned int)(uintptr_t)l,
        16, 0, 0);
}

// ---------------------------------------------------------------------------
// fp32 -> bf16 elementwise (vec4)
// ---------------------------------------------------------------------------
__global__ __launch_bounds__(256) void cvt_bf16_kernel(
    const float* __restrict__ src, unsigned short* __restrict__ dst, int n4)
{
    int i = blockIdx.x * 256 + threadIdx.x;
    if (i < n4) {
        float4 v = ((const float4*)src)[i];
        ushort4 o;
        o.x = f2bf(v.x); o.y = f2bf(v.y); o.z = f2bf(v.z); o.w = f2bf(v.w);
        ((ushort4*)dst)[i] = o;
    }
}

// ---------------------------------------------------------------------------
// fp32 W[K=1024][N=1024] -> bf16 Wt[N][K] (transpose + downcast), 32x32 tiles
// ---------------------------------------------------------------------------
__global__ __launch_bounds__(256) void transpose_bf16_kernel(
    const float* __restrict__ W, unsigned short* __restrict__ Wt)
{
    __shared__ unsigned short tile[32][33];
    const int bn = blockIdx.x * 32;
    const int bk = blockIdx.y * 32;
    const int tx = threadIdx.x & 31, ty = threadIdx.x >> 5;
    #pragma unroll
    for (int r = ty; r < 32; r += 8)
        tile[tx][r] = f2bf(W[(size_t)(bk + r) * D_ + bn + tx]);
    __syncthreads();
    #pragma unroll
    for (int r = ty; r < 32; r += 8)
        Wt[(size_t)(bn + r) * D_ + bk + tx] = tile[r][tx];
}

// ---------------------------------------------------------------------------
// bf16 MFMA GEMM (m97 structure): C[M,N] = A[M,K] @ Bt[N,K]^T, C fp32.
// 128x128 tile, BK=32, 256 thr (4 waves, 2x2), 4x4 16x16 frags per wave.
// ---------------------------------------------------------------------------
__global__ __launch_bounds__(256) void gemm_bf16_kernel(
    const unsigned short* __restrict__ A,   // [M,K] bf16 bits
    const unsigned short* __restrict__ Bt,  // [N,K] bf16 bits
    float* __restrict__ C, int M, int N, int K)
{
    __shared__ unsigned short As[128 * 32];
    __shared__ unsigned short Bs[128 * 32];
    const int bm = blockIdx.y * 128;
    const int bn = blockIdx.x * 128;
    const int t = threadIdx.x;
    const int wv = t >> 6, lane = t & 63;
    const int q  = lane >> 4, ml = lane & 15;
    const int wm = (wv >> 1) * 64, wn = (wv & 1) * 64;
    const int row4 = t >> 2;
    const int kof  = (t & 3) * 8;
    f32x4 acc[4][4] = {};
    for (int k0 = 0; k0 < K; k0 += 32) {
        __syncthreads();
        #pragma unroll
        for (int i = 0; i < 2; ++i) {
            const unsigned short* ga = A  + (size_t)(bm + i * 64 + row4) * K + k0 + kof;
            const unsigned short* gb = Bt + (size_t)(bn + i * 64 + row4) * K + k0 + kof;
            gl_lds16(ga, &As[(i * 256 + wv * 64) * 8]);
            gl_lds16(gb, &Bs[(i * 256 + wv * 64) * 8]);
        }
        __syncthreads();
        bf16x8 af[4], bfr[4];
        #pragma unroll
        for (int i = 0; i < 4; ++i)
            af[i] = *(const bf16x8*)&As[(wm + i * 16 + ml) * 32 + q * 8];
        #pragma unroll
        for (int j = 0; j < 4; ++j)
            bfr[j] = *(const bf16x8*)&Bs[(wn + j * 16 + ml) * 32 + q * 8];
        #pragma unroll
        for (int i = 0; i < 4; ++i)
            #pragma unroll
            for (int j = 0; j < 4; ++j)
                acc[i][j] = __builtin_amdgcn_mfma_f32_16x16x32_bf16(af[i], bfr[j], acc[i][j], 0, 0, 0);
    }
    #pragma unroll
    for (int i = 0; i < 4; ++i) {
        #pragma unroll
        for (int r = 0; r < 4; ++r) {
            const int row = bm + wm + i * 16 + q * 4 + r;
            float* cp = C + (size_t)row * N + bn + wn + ml;
            #pragma unroll
            for (int j = 0; j < 4; ++j)
                cp[j * 16] = acc[i][j][r];
        }
    }
}

// ---------------------------------------------------------------------------
// W3t[48][1024] bf16: rows 0-15 = Wb^T, 16-31 = Wfd^T, 32-47 = Wsd^T
// ---------------------------------------------------------------------------
__global__ __launch_bounds__(256) void proj_prep_kernel(
    const float* __restrict__ Wb, const float* __restrict__ Wfd,
    const float* __restrict__ Wsd, unsigned short* __restrict__ W3t)
{
    int i = blockIdx.x * 256 + threadIdx.x;   // 48*1024
    int c = i >> 10, k = i & 1023;
    const float* W = c < 16 ? Wb : (c < 32 ? Wfd : Wsd);
    W3t[i] = f2bf(W[k * H_ + (c & 15)]);
}

// ---------------------------------------------------------------------------
// Small projections via MFMA: C[8192 x 48] = xb @ W3t^T; sigmoid(+bias).
// 64-token tile per block, 4 waves (16 tok each), 3 n-tiles, K=1024.
// j=0 -> beta, j=1 -> fastd (+bfd), j=2 -> slowd (+bsd); layout [bh][l].
// ---------------------------------------------------------------------------
__global__ __launch_bounds__(256) void proj_mfma_kernel(
    const unsigned short* __restrict__ xb, const unsigned short* __restrict__ W3t,
    const float* __restrict__ bfd, const float* __restrict__ bsd,
    float* __restrict__ beta, float* __restrict__ fastd, float* __restrict__ slowd)
{
    __shared__ unsigned short xs[64 * 32];
    __shared__ unsigned short wsh[48 * 32];
    const int t = threadIdx.x, wv = t >> 6, lane = t & 63;
    const int q = lane >> 4, ml = lane & 15;
    const int r0 = blockIdx.x * 64;
    f32x4 acc[3] = {};
    for (int k0 = 0; k0 < D_; k0 += 32) {
        __syncthreads();
        gl_lds16(xb + (size_t)(r0 + wv * 16 + (lane >> 2)) * D_ + k0 + (lane & 3) * 8,
                 &xs[wv * 512]);
        if (wv < 3)
            gl_lds16(W3t + (size_t)(wv * 16 + (lane >> 2)) * D_ + k0 + (lane & 3) * 8,
                     &wsh[wv * 512]);
        __syncthreads();
        bf16x8 af = *(const bf16x8*)&xs[(wv * 16 + ml) * 32 + q * 8];
        #pragma unroll
        for (int j = 0; j < 3; ++j) {
            bf16x8 bfr = *(const bf16x8*)&wsh[(j * 16 + ml) * 32 + q * 8];
            acc[j] = __builtin_amdgcn_mfma_f32_16x16x32_bf16(af, bfr, acc[j], 0, 0, 0);
        }
    }
    #pragma unroll
    for (int j = 0; j < 3; ++j) {
        #pragma unroll
        for (int r = 0; r < 4; ++r) {
            const int rg = r0 + wv * 16 + q * 4 + r;
            float v = acc[j][r];
            if (j == 1) v += bfd[ml];
            if (j == 2) v += bsd[ml];
            const float sg = 1.f / (1.f + expf(-v));
            const int b = rg >> 12, l = rg & (L_ - 1);
            float* dst = j == 0 ? beta : (j == 1 ? fastd : slowd);
            dst[(size_t)(b * H_ + ml) * L_ + l] = sg;
        }
    }
}

// ---------------------------------------------------------------------------
// Per-(b,h) scan of log(decay+1e-6); w = exp(total - cs); denom = sum(w)+1e-6.
// ---------------------------------------------------------------------------
__global__ __launch_bounds__(256) void scan_kernel(
    const float* __restrict__ fastd, const float* __restrict__ slowd,
    float* __restrict__ fw, float* __restrict__ sw, float* __restrict__ denom)
{
    __shared__ float part[256];
    const int bh = blockIdx.x >> 1;
    const int which = blockIdx.x & 1;
    const float* src = (which ? slowd : fastd) + (size_t)bh * L_;
    float* dst = (which ? sw : fw) + (size_t)bh * L_;
    const int t = threadIdx.x;
    float vals[16];
    float run = 0.f;
    #pragma unroll
    for (int i = 0; i < 16; ++i) {
        run += logf(src[t * 16 + i] + 1e-6f);
        vals[i] = run;
    }
    part[t] = run;
    __syncthreads();
    for (int off = 1; off < 256; off <<= 1) {
        float v = (t >= off) ? part[t - off] : 0.f;
        __syncthreads();
        part[t] += v;
        __syncthreads();
    }
    const float excl = part[t] - run;
    const float total = part[255];
    __syncthreads();
    float lsum = 0.f;
    #pragma unroll
    for (int i = 0; i < 16; ++i) {
        float w = expf(total - (vals[i] + excl));
        dst[t * 16 + i] = w;
        lsum += w;
    }
    part[t] = lsum;
    __syncthreads();
    for (int off = 128; off > 0; off >>= 1) {
        if (t < off) part[t] += part[t + off];
        __syncthreads();
    }
    if (t == 0) denom[bh * 2 + which] = part[0] + 1e-6f;
}

// ---------------------------------------------------------------------------
// Per-(token,head) wave: l2norm q,k; k_beta, v_scaled; token-flux MLP -> alpha.
// ---------------------------------------------------------------------------
__global__ __launch_bounds__(256) void normflux_kernel(
    float* __restrict__ Q, float* __restrict__ Kb, float* __restrict__ Vb,
    const float* __restrict__ beta,
    const float* __restrict__ Wtf1, const float* __restrict__ btf1,
    const float* __restrict__ Wtf2, const float* __restrict__ btf2,
    float* __restrict__ alphaA)
{
    __shared__ float kbs[4][64];
    const int wv = threadIdx.x >> 6;
    const int lane = threadIdx.x & 63;
    const int w = blockIdx.x * 4 + wv;
    const int r = w >> 4;
    const int h = w & 15;
    const int b = r >> 12;
    const int l = r & (L_ - 1);
    const int bh = b * H_ + h;
    const size_t idx = (size_t)r * D_ + h * DK_ + lane;
    const float qv = Q[idx], kv = Kb[idx], vv = Vb[idx];
    const float qs = wave_sum(qv * qv);
    const float ks = wave_sum(kv * kv);
    const float qn = qv / fmaxf(sqrtf(qs), 1e-12f);
    const float kn = kv / fmaxf(sqrtf(ks), 1e-12f);
    const float bt = beta[(size_t)bh * L_ + l];
    const float kb = kn * bt;
    Q[idx] = qn; Kb[idx] = kb; Vb[idx] = vv * bt;
    kbs[wv][lane] = kb;
    __syncthreads();
    float hm = 0.f;
    if (lane < 32) {
        float acc = btf1[lane];
        #pragma unroll 8
        for (int i = 0; i < 64; ++i)
            acc = fmaf(kbs[wv][i], Wtf1[i * 32 + lane], acc);
        const float sg = 1.f / (1.f + expf(-acc));
        hm = acc * sg * Wtf2[lane];
    }
    const float tfs = wave_sum(hm);
    float tf = 1.f / (1.f + expf(-(tfs + btf2[0])));
    tf = fminf(fmaxf(tf, 0.01f), 0.99f);
    if (lane == 0) alphaA[(size_t)bh * L_ + l] = 0.5f + 0.3f * tf;
}

// ---------------------------------------------------------------------------
// Transpose+scale: kfT/ksT/vT[bh][d][l] (bf16) from Kb,Vb (fp32) and fw,sw.
// Block = (h, b, 64-l chunk); LDS tile with +1 pad.
// ---------------------------------------------------------------------------
__global__ __launch_bounds__(256) void tfx_kernel(
    const float* __restrict__ Kb, const float* __restrict__ Vb,
    const float* __restrict__ fw, const float* __restrict__ sw,
    unsigned short* __restrict__ kfT, unsigned short* __restrict__ ksT,
    unsigned short* __restrict__ vT)
{
    __shared__ float kb_s[64][65];
    __shared__ float vb_s[64][65];
    __shared__ float fws[64], sws[64];
    const int h = blockIdx.x, b = blockIdx.y, lc = blockIdx.z;
    const int l0 = lc * 64;
    const int bh = b * H_ + h;
    const int t = threadIdx.x;
    {
        const int ll = t >> 2, dq = (t & 3) * 16;
        const float* kp = Kb + (size_t)(b * L_ + l0 + ll) * D_ + h * DK_ + dq;
        const float* vp = Vb + (size_t)(b * L_ + l0 + ll) * D_ + h * DK_ + dq;
        #pragma unroll
        for (int u = 0; u < 4; ++u) {
            float4 kv = ((const float4*)kp)[u];
            float4 vv = ((const float4*)vp)[u];
            kb_s[ll][dq + u * 4 + 0] = kv.x; kb_s[ll][dq + u * 4 + 1] = kv.y;
            kb_s[ll][dq + u * 4 + 2] = kv.z; kb_s[ll][dq + u * 4 + 3] = kv.w;
            vb_s[ll][dq + u * 4 + 0] = vv.x; vb_s[ll][dq + u * 4 + 1] = vv.y;
            vb_s[ll][dq + u * 4 + 2] = vv.z; vb_s[ll][dq + u * 4 + 3] = vv.w;
        }
        if (t < 64) {
            fws[t] = fw[(size_t)bh * L_ + l0 + t];
            sws[t] = sw[(size_t)bh * L_ + l0 + t];
        }
    }
    __syncthreads();
    const int d = t >> 2, lq = (t & 3) * 16;
    __align__(16) unsigned short bF[16], bS[16], bV[16];
    #pragma unroll
    for (int j = 0; j < 16; ++j) {
        const int l = lq + j;
        const float kv = kb_s[l][d];
        bF[j] = f2bf(kv * fws[l]);
        bS[j] = f2bf(kv * sws[l]);
        bV[j] = f2bf(vb_s[l][d]);
    }
    const size_t base = ((size_t)bh * DK_ + d) * L_ + l0 + lq;
    *(uint4*)(kfT + base) = *(const uint4*)&bF[0];
    *(uint4*)(kfT + base + 8) = *(const uint4*)&bF[8];
    *(uint4*)(ksT + base) = *(const uint4*)&bS[0];
    *(uint4*)(ksT + base + 8) = *(const uint4*)&bS[8];
    *(uint4*)(vT + base) = *(const uint4*)&bV[0];
    *(uint4*)(vT + base + 8) = *(const uint4*)&bV[8];
}

// ---------------------------------------------------------------------------
// M_fast/M_slow via MFMA: M[d][e] = sum_l kT[d][l] * vT[e][l].
// Grid (bh, 16 L-segs); block 4 waves in 2x2 (32d x 32e each), both states.
// fp32 atomicAdd epilogue.
// ---------------------------------------------------------------------------
__global__ __launch_bounds__(256) void mstate_mfma_kernel(
    const unsigned short* __restrict__ kfT, const unsigned short* __restrict__ ksT,
    const unsigned short* __restrict__ vT,
    float* __restrict__ Mf, float* __restrict__ Ms)
{
    __shared__ unsigned short kf_s[64 * 32];
    __shared__ unsigned short ks_s[64 * 32];
    __shared__ unsigned short v_s[64 * 32];
    const int bh = blockIdx.x;
    const int seg = blockIdx.y;            // 16 segs x 256 l
    const int t = threadIdx.x, wv = t >> 6, lane = t & 63;
    const int q = lane >> 4, ml = lane & 15;
    const int wm = (wv >> 1) * 32, wn = (wv & 1) * 32;
    const size_t hb = (size_t)bh * DK_ * L_;
    const size_t grow = hb + (size_t)(wv * 16 + (lane >> 2)) * L_ + (lane & 3) * 8;
    f32x4 aF[2][2] = {}, aS[2][2] = {};
    for (int l0 = seg * 256; l0 < seg * 256 + 256; l0 += 32) {
        __syncthreads();
        gl_lds16(kfT + grow + l0, &kf_s[wv * 512]);
        gl_lds16(ksT + grow + l0, &ks_s[wv * 512]);
        gl_lds16(vT  + grow + l0, &v_s[wv * 512]);
        __syncthreads();
        bf16x8 fa[2], sa[2], vb[2];
        #pragma unroll
        for (int i = 0; i < 2; ++i) {
            fa[i] = *(const bf16x8*)&kf_s[(wm + i * 16 + ml) * 32 + q * 8];
            sa[i] = *(const bf16x8*)&ks_s[(wm + i * 16 + ml) * 32 + q * 8];
            vb[i] = *(const bf16x8*)&v_s[(wn + i * 16 + ml) * 32 + q * 8];
        }
        #pragma unroll
        for (int i = 0; i < 2; ++i)
            #pragma unroll
            for (int j = 0; j < 2; ++j) {
                aF[i][j] = __builtin_amdgcn_mfma_f32_16x16x32_bf16(fa[i], vb[j], aF[i][j], 0, 0, 0);
                aS[i][j] = __builtin_amdgcn_mfma_f32_16x16x32_bf16(sa[i], vb[j], aS[i][j], 0, 0, 0);
            }
    }
    #pragma unroll
    for (int i = 0; i < 2; ++i)
        #pragma unroll
        for (int j = 0; j < 2; ++j)
            #pragma unroll
            for (int r = 0; r < 4; ++r) {
                const int d = wm + i * 16 + q * 4 + r;
                const int e = wn + j * 16 + ml;
                atomicAdd(&Mf[(size_t)bh * (DK_ * DK_) + d * DK_ + e], aF[i][j][r]);
                atomicAdd(&Ms[(size_t)bh * (DK_ * DK_) + d * DK_ + e], aS[i][j][r]);
            }
}

// ---------------------------------------------------------------------------
// o = alpha*(q@Mf)/dF + (1-alpha)*(q@Ms)/dS, written as bf16 for final GEMM.
// ---------------------------------------------------------------------------
__global__ __launch_bounds__(256) void o_kernel(
    const float* __restrict__ Q, const float* __restrict__ Mf, const float* __restrict__ Ms,
    const float* __restrict__ alphaA, const float* __restrict__ denom,
    unsigned short* __restrict__ Ob)
{
    __shared__ float Mfs[DK_ * DK_];
    __shared__ float Mss[DK_ * DK_];
    const int bh = blockIdx.x;
    const int b = bh >> 4, h = bh & 15;
    for (int i = threadIdx.x; i < DK_ * DK_; i += 256) {
        Mfs[i] = Mf[(size_t)bh * (DK_ * DK_) + i];
        Mss[i] = Ms[(size_t)bh * (DK_ * DK_) + i];
    }
    __syncthreads();
    const float dF = denom[bh * 2 + 0], dS = denom[bh * 2 + 1];
    const int wv = threadIdx.x >> 6, lane = threadIdx.x & 63;
    for (int it = 0; it < 8; ++it) {
        const int l = blockIdx.y * 32 + wv * 8 + it;
        const size_t idx = (size_t)(b * L_ + l) * D_ + h * DK_ + lane;
        const float qv = Q[idx];
        float of = 0.f, os = 0.f;
        #pragma unroll 16
        for (int d = 0; d < 64; ++d) {
            const float qd = __shfl(qv, d, 64);
            of = fmaf(qd, Mfs[d * 64 + lane], of);
            os = fmaf(qd, Mss[d * 64 + lane], os);
        }
        const float a = alphaA[(size_t)bh * L_ + l];
        Ob[idx] = f2bf(a * (of / dF) + (1.f - a) * (os / dS));
    }
}

extern "C" void kernel_launch(void* const* d_in, const int* in_sizes, int n_in,
                              void* d_out, int out_size, void* d_ws, size_t ws_size,
                              hipStream_t stream)
{
    const float* x    = (const float*)d_in[0];
    const float* Wq   = (const float*)d_in[1];
    const float* Wk   = (const float*)d_in[2];
    const float* Wv   = (const float*)d_in[3];
    const float* Wb   = (const float*)d_in[4];
    const float* Wo   = (const float*)d_in[5];
    const float* Wfd  = (const float*)d_in[6];
    const float* bfd  = (const float*)d_in[7];
    const float* Wsd  = (const float*)d_in[8];
    const float* bsd  = (const float*)d_in[9];
    const float* Wtf1 = (const float*)d_in[10];
    const float* btf1 = (const float*)d_in[11];
    const float* Wtf2 = (const float*)d_in[12];
    const float* btf2 = (const float*)d_in[13];
    float* out        = (float*)d_out;

    char* w = (char*)d_ws;
    float* Q   = (float*)w;  w += (size_t)R_ * D_ * 4;
    float* Kb  = (float*)w;  w += (size_t)R_ * D_ * 4;
    float* Vb  = (float*)w;  w += (size_t)R_ * D_ * 4;
    unsigned short* xb  = (unsigned short*)w; w += (size_t)R_ * D_ * 2;  // reused as Ob
    unsigned short* Wtq = (unsigned short*)w; w += (size_t)D_ * D_ * 2;
    unsigned short* Wtk = (unsigned short*)w; w += (size_t)D_ * D_ * 2;
    unsigned short* Wtv = (unsigned short*)w; w += (size_t)D_ * D_ * 2;
    unsigned short* Wto = (unsigned short*)w; w += (size_t)D_ * D_ * 2;
    unsigned short* kfT = (unsigned short*)w; w += (size_t)32 * DK_ * L_ * 2;
    unsigned short* ksT = (unsigned short*)w; w += (size_t)32 * DK_ * L_ * 2;
    unsigned short* vT  = (unsigned short*)w; w += (size_t)32 * DK_ * L_ * 2;
    unsigned short* W3t = (unsigned short*)w; w += (size_t)48 * D_ * 2;
    float* beta   = (float*)w; w += 32 * L_ * 4;
    float* fastd  = (float*)w; w += 32 * L_ * 4;
    float* slowd  = (float*)w; w += 32 * L_ * 4;
    float* fw     = (float*)w; w += 32 * L_ * 4;
    float* sw     = (float*)w; w += 32 * L_ * 4;
    float* alphaA = (float*)w; w += 32 * L_ * 4;
    float* Mf     = (float*)w; w += 32 * DK_ * DK_ * 4;
    float* Ms     = (float*)w; w += 32 * DK_ * DK_ * 4;
    float* denom  = (float*)w; w += 64 * 4;

    // prep: bf16 conversions / transposes
    cvt_bf16_kernel<<<R_ * D_ / 4 / 256, 256, 0, stream>>>(x, xb, R_ * D_ / 4);
    transpose_bf16_kernel<<<dim3(32, 32), 256, 0, stream>>>(Wq, Wtq);
    transpose_bf16_kernel<<<dim3(32, 32), 256, 0, stream>>>(Wk, Wtk);
    transpose_bf16_kernel<<<dim3(32, 32), 256, 0, stream>>>(Wv, Wtv);
    transpose_bf16_kernel<<<dim3(32, 32), 256, 0, stream>>>(Wo, Wto);
    proj_prep_kernel<<<48 * 1024 / 256, 256, 0, stream>>>(Wb, Wfd, Wsd, W3t);

    // small projections + scan (independent of big GEMMs)
    proj_mfma_kernel<<<R_ / 64, 256, 0, stream>>>(xb, W3t, bfd, bsd, beta, fastd, slowd);
    scan_kernel<<<64, 256, 0, stream>>>(fastd, slowd, fw, sw, denom);

    // QKV projections
    gemm_bf16_kernel<<<dim3(D_ / 128, R_ / 128), 256, 0, stream>>>(xb, Wtq, Q,  R_, D_, D_);
    gemm_bf16_kernel<<<dim3(D_ / 128, R_ / 128), 256, 0, stream>>>(xb, Wtk, Kb, R_, D_, D_);
    gemm_bf16_kernel<<<dim3(D_ / 128, R_ / 128), 256, 0, stream>>>(xb, Wtv, Vb, R_, D_, D_);

    normflux_kernel<<<R_ * H_ / 4, 256, 0, stream>>>(Q, Kb, Vb, beta, Wtf1, btf1, Wtf2, btf2, alphaA);
    tfx_kernel<<<dim3(H_, B_, L_ / 64), 256, 0, stream>>>(Kb, Vb, fw, sw, kfT, ksT, vT);
    (void)hipMemsetAsync(Mf, 0, 2 * 32 * DK_ * DK_ * sizeof(float), stream);
    mstate_mfma_kernel<<<dim3(32, 16), 256, 0, stream>>>(kfT, ksT, vT, Mf, Ms);
    o_kernel<<<dim3(32, 128), 256, 0, stream>>>(Q, Mf, Ms, alphaA, denom, xb);
    gemm_bf16_kernel<<<dim3(D_ / 128, R_ / 128), 256, 0, stream>>>(xb, Wto, out, R_, D_, D_);
}

// Round 6
// 421.311 us; speedup vs baseline: 4.5416x; 1.3149x over previous
//
#include <hip/hip_runtime.h>
#include <hip/hip_bf16.h>

#define B_ 2
#define L_ 4096
#define D_ 1024
#define H_ 16
#define DK_ 64
#define R_ (B_*L_)   // 8192 tokens

typedef __bf16 bf16x8 __attribute__((ext_vector_type(8)));
typedef float  f32x4  __attribute__((ext_vector_type(4)));

__device__ __forceinline__ float wave_sum(float v) {
    #pragma unroll
    for (int off = 32; off > 0; off >>= 1) v += __shfl_xor(v, off, 64);
    return v;
}

__device__ __forceinline__ unsigned short f2bf(float f) {   // RNE
    unsigned int u = __float_as_uint(f);
    return (unsigned short)((u + 0x7fffu + ((u >> 16) & 1u)) >> 16);
}

// async global->LDS, 16 B per lane; LDS dest = wave-uniform base + lane*16
__device__ __forceinline__ void gl_lds16(const void* g, void* l) {
    __builtin_amdgcn_global_load_lds(
        (const __attribute__((address_space(1))) void*)(uintptr_t)g,
        (__attribute__((address_space(3))) void*)(unsigned int)(uintptr_t)l,
        16, 0, 0);
}

// ---------------------------------------------------------------------------
// fp32 -> bf16 elementwise (vec4)
// ---------------------------------------------------------------------------
__global__ __launch_bounds__(256) void cvt_bf16_kernel(
    const float* __restrict__ src, unsigned short* __restrict__ dst, int n4)
{
    int i = blockIdx.x * 256 + threadIdx.x;
    if (i < n4) {
        float4 v = ((const float4*)src)[i];
        ushort4 o;
        o.x = f2bf(v.x); o.y = f2bf(v.y); o.z = f2bf(v.z); o.w = f2bf(v.w);
        ((ushort4*)dst)[i] = o;
    }
}

// ---------------------------------------------------------------------------
// fp32 W[K=1024][N=1024] -> bf16 Wt[N][K] (transpose + downcast), 32x32 tiles
// ---------------------------------------------------------------------------
__global__ __launch_bounds__(256) void transpose_bf16_kernel(
    const float* __restrict__ W, unsigned short* __restrict__ Wt)
{
    __shared__ unsigned short tile[32][33];
    const int bn = blockIdx.x * 32;
    const int bk = blockIdx.y * 32;
    const int tx = threadIdx.x & 31, ty = threadIdx.x >> 5;
    #pragma unroll
    for (int r = ty; r < 32; r += 8)
        tile[tx][r] = f2bf(W[(size_t)(bk + r) * D_ + bn + tx]);
    __syncthreads();
    #pragma unroll
    for (int r = ty; r < 32; r += 8)
        Wt[(size_t)(bn + r) * D_ + bk + tx] = tile[r][tx];
}

// ---------------------------------------------------------------------------
// bf16 MFMA GEMM (m97 structure): C[M,N] = A[M,K] @ Bt[N,K]^T, C fp32.
// 128x128 tile, BK=32, 256 thr (4 waves, 2x2), 4x4 16x16 frags per wave.
// ---------------------------------------------------------------------------
__global__ __launch_bounds__(256) void gemm_bf16_kernel(
    const unsigned short* __restrict__ A,   // [M,K] bf16 bits
    const unsigned short* __restrict__ Bt,  // [N,K] bf16 bits
    float* __restrict__ C, int M, int N, int K)
{
    __shared__ unsigned short As[128 * 32];
    __shared__ unsigned short Bs[128 * 32];
    const int bm = blockIdx.y * 128;
    const int bn = blockIdx.x * 128;
    const int t = threadIdx.x;
    const int wv = t >> 6, lane = t & 63;
    const int q  = lane >> 4, ml = lane & 15;
    const int wm = (wv >> 1) * 64, wn = (wv & 1) * 64;
    const int row4 = t >> 2;
    const int kof  = (t & 3) * 8;
    f32x4 acc[4][4] = {};
    for (int k0 = 0; k0 < K; k0 += 32) {
        __syncthreads();
        #pragma unroll
        for (int i = 0; i < 2; ++i) {
            const unsigned short* ga = A  + (size_t)(bm + i * 64 + row4) * K + k0 + kof;
            const unsigned short* gb = Bt + (size_t)(bn + i * 64 + row4) * K + k0 + kof;
            gl_lds16(ga, &As[(i * 256 + wv * 64) * 8]);
            gl_lds16(gb, &Bs[(i * 256 + wv * 64) * 8]);
        }
        __syncthreads();
        bf16x8 af[4], bfr[4];
        #pragma unroll
        for (int i = 0; i < 4; ++i)
            af[i] = *(const bf16x8*)&As[(wm + i * 16 + ml) * 32 + q * 8];
        #pragma unroll
        for (int j = 0; j < 4; ++j)
            bfr[j] = *(const bf16x8*)&Bs[(wn + j * 16 + ml) * 32 + q * 8];
        #pragma unroll
        for (int i = 0; i < 4; ++i)
            #pragma unroll
            for (int j = 0; j < 4; ++j)
                acc[i][j] = __builtin_amdgcn_mfma_f32_16x16x32_bf16(af[i], bfr[j], acc[i][j], 0, 0, 0);
    }
    #pragma unroll
    for (int i = 0; i < 4; ++i) {
        #pragma unroll
        for (int r = 0; r < 4; ++r) {
            const int row = bm + wm + i * 16 + q * 4 + r;
            float* cp = C + (size_t)row * N + bn + wn + ml;
            #pragma unroll
            for (int j = 0; j < 4; ++j)
                cp[j * 16] = acc[i][j][r];
        }
    }
}

// ---------------------------------------------------------------------------
// W3t[48][1024] bf16: rows 0-15 = Wb^T, 16-31 = Wfd^T, 32-47 = Wsd^T
// ---------------------------------------------------------------------------
__global__ __launch_bounds__(256) void proj_prep_kernel(
    const float* __restrict__ Wb, const float* __restrict__ Wfd,
    const float* __restrict__ Wsd, unsigned short* __restrict__ W3t)
{
    int i = blockIdx.x * 256 + threadIdx.x;   // 48*1024
    int c = i >> 10, k = i & 1023;
    const float* W = c < 16 ? Wb : (c < 32 ? Wfd : Wsd);
    W3t[i] = f2bf(W[k * H_ + (c & 15)]);
}

// ---------------------------------------------------------------------------
// Small projections via MFMA: C[8192 x 48] = xb @ W3t^T; sigmoid(+bias).
// ---------------------------------------------------------------------------
__global__ __launch_bounds__(256) void proj_mfma_kernel(
    const unsigned short* __restrict__ xb, const unsigned short* __restrict__ W3t,
    const float* __restrict__ bfd, const float* __restrict__ bsd,
    float* __restrict__ beta, float* __restrict__ fastd, float* __restrict__ slowd)
{
    __shared__ unsigned short xs[64 * 32];
    __shared__ unsigned short wsh[48 * 32];
    const int t = threadIdx.x, wv = t >> 6, lane = t & 63;
    const int q = lane >> 4, ml = lane & 15;
    const int r0 = blockIdx.x * 64;
    f32x4 acc[3] = {};
    for (int k0 = 0; k0 < D_; k0 += 32) {
        __syncthreads();
        gl_lds16(xb + (size_t)(r0 + wv * 16 + (lane >> 2)) * D_ + k0 + (lane & 3) * 8,
                 &xs[wv * 512]);
        if (wv < 3)
            gl_lds16(W3t + (size_t)(wv * 16 + (lane >> 2)) * D_ + k0 + (lane & 3) * 8,
                     &wsh[wv * 512]);
        __syncthreads();
        bf16x8 af = *(const bf16x8*)&xs[(wv * 16 + ml) * 32 + q * 8];
        #pragma unroll
        for (int j = 0; j < 3; ++j) {
            bf16x8 bfr = *(const bf16x8*)&wsh[(j * 16 + ml) * 32 + q * 8];
            acc[j] = __builtin_amdgcn_mfma_f32_16x16x32_bf16(af, bfr, acc[j], 0, 0, 0);
        }
    }
    #pragma unroll
    for (int j = 0; j < 3; ++j) {
        #pragma unroll
        for (int r = 0; r < 4; ++r) {
            const int rg = r0 + wv * 16 + q * 4 + r;
            float v = acc[j][r];
            if (j == 1) v += bfd[ml];
            if (j == 2) v += bsd[ml];
            const float sg = 1.f / (1.f + expf(-v));
            const int b = rg >> 12, l = rg & (L_ - 1);
            float* dst = j == 0 ? beta : (j == 1 ? fastd : slowd);
            dst[(size_t)(b * H_ + ml) * L_ + l] = sg;
        }
    }
}

// ---------------------------------------------------------------------------
// Per-(b,h) scan of log(decay+1e-6); w = exp(total - cs); denom = sum(w)+1e-6.
// ---------------------------------------------------------------------------
__global__ __launch_bounds__(256) void scan_kernel(
    const float* __restrict__ fastd, const float* __restrict__ slowd,
    float* __restrict__ fw, float* __restrict__ sw, float* __restrict__ denom)
{
    __shared__ float part[256];
    const int bh = blockIdx.x >> 1;
    const int which = blockIdx.x & 1;
    const float* src = (which ? slowd : fastd) + (size_t)bh * L_;
    float* dst = (which ? sw : fw) + (size_t)bh * L_;
    const int t = threadIdx.x;
    float vals[16];
    float run = 0.f;
    #pragma unroll
    for (int i = 0; i < 16; ++i) {
        run += logf(src[t * 16 + i] + 1e-6f);
        vals[i] = run;
    }
    part[t] = run;
    __syncthreads();
    for (int off = 1; off < 256; off <<= 1) {
        float v = (t >= off) ? part[t - off] : 0.f;
        __syncthreads();
        part[t] += v;
        __syncthreads();
    }
    const float excl = part[t] - run;
    const float total = part[255];
    __syncthreads();
    float lsum = 0.f;
    #pragma unroll
    for (int i = 0; i < 16; ++i) {
        float w = expf(total - (vals[i] + excl));
        dst[t * 16 + i] = w;
        lsum += w;
    }
    part[t] = lsum;
    __syncthreads();
    for (int off = 128; off > 0; off >>= 1) {
        if (t < off) part[t] += part[t + off];
        __syncthreads();
    }
    if (t == 0) denom[bh * 2 + which] = part[0] + 1e-6f;
}

// ---------------------------------------------------------------------------
// Per-(token,head) wave: l2norm q,k; k_beta, v_scaled; token-flux MLP -> alpha.
// Normalized q written as bf16 (qb) for the o MFMA.
// ---------------------------------------------------------------------------
__global__ __launch_bounds__(256) void normflux_kernel(
    const float* __restrict__ Q, float* __restrict__ Kb, float* __restrict__ Vb,
    const float* __restrict__ beta,
    const float* __restrict__ Wtf1, const float* __restrict__ btf1,
    const float* __restrict__ Wtf2, const float* __restrict__ btf2,
    float* __restrict__ alphaA, unsigned short* __restrict__ qb)
{
    __shared__ float kbs[4][64];
    const int wv = threadIdx.x >> 6;
    const int lane = threadIdx.x & 63;
    const int w = blockIdx.x * 4 + wv;
    const int r = w >> 4;
    const int h = w & 15;
    const int b = r >> 12;
    const int l = r & (L_ - 1);
    const int bh = b * H_ + h;
    const size_t idx = (size_t)r * D_ + h * DK_ + lane;
    const float qv = Q[idx], kv = Kb[idx], vv = Vb[idx];
    const float qs = wave_sum(qv * qv);
    const float ks = wave_sum(kv * kv);
    const float qn = qv / fmaxf(sqrtf(qs), 1e-12f);
    const float kn = kv / fmaxf(sqrtf(ks), 1e-12f);
    const float bt = beta[(size_t)bh * L_ + l];
    const float kb = kn * bt;
    qb[idx] = f2bf(qn);
    Kb[idx] = kb; Vb[idx] = vv * bt;
    kbs[wv][lane] = kb;
    __syncthreads();
    float hm = 0.f;
    if (lane < 32) {
        float acc = btf1[lane];
        #pragma unroll 8
        for (int i = 0; i < 64; ++i)
            acc = fmaf(kbs[wv][i], Wtf1[i * 32 + lane], acc);
        const float sg = 1.f / (1.f + expf(-acc));
        hm = acc * sg * Wtf2[lane];
    }
    const float tfs = wave_sum(hm);
    float tf = 1.f / (1.f + expf(-(tfs + btf2[0])));
    tf = fminf(fmaxf(tf, 0.01f), 0.99f);
    if (lane == 0) alphaA[(size_t)bh * L_ + l] = 0.5f + 0.3f * tf;
}

// ---------------------------------------------------------------------------
// Transpose+scale: kfT/ksT/vT[bh][d][l] (bf16) from Kb,Vb (fp32) and fw,sw.
// ---------------------------------------------------------------------------
__global__ __launch_bounds__(256) void tfx_kernel(
    const float* __restrict__ Kb, const float* __restrict__ Vb,
    const float* __restrict__ fw, const float* __restrict__ sw,
    unsigned short* __restrict__ kfT, unsigned short* __restrict__ ksT,
    unsigned short* __restrict__ vT)
{
    __shared__ float kb_s[64][65];
    __shared__ float vb_s[64][65];
    __shared__ float fws[64], sws[64];
    const int h = blockIdx.x, b = blockIdx.y, lc = blockIdx.z;
    const int l0 = lc * 64;
    const int bh = b * H_ + h;
    const int t = threadIdx.x;
    {
        const int ll = t >> 2, dq = (t & 3) * 16;
        const float* kp = Kb + (size_t)(b * L_ + l0 + ll) * D_ + h * DK_ + dq;
        const float* vp = Vb + (size_t)(b * L_ + l0 + ll) * D_ + h * DK_ + dq;
        #pragma unroll
        for (int u = 0; u < 4; ++u) {
            float4 kv = ((const float4*)kp)[u];
            float4 vv = ((const float4*)vp)[u];
            kb_s[ll][dq + u * 4 + 0] = kv.x; kb_s[ll][dq + u * 4 + 1] = kv.y;
            kb_s[ll][dq + u * 4 + 2] = kv.z; kb_s[ll][dq + u * 4 + 3] = kv.w;
            vb_s[ll][dq + u * 4 + 0] = vv.x; vb_s[ll][dq + u * 4 + 1] = vv.y;
            vb_s[ll][dq + u * 4 + 2] = vv.z; vb_s[ll][dq + u * 4 + 3] = vv.w;
        }
        if (t < 64) {
            fws[t] = fw[(size_t)bh * L_ + l0 + t];
            sws[t] = sw[(size_t)bh * L_ + l0 + t];
        }
    }
    __syncthreads();
    const int d = t >> 2, lq = (t & 3) * 16;
    __align__(16) unsigned short bF[16], bS[16], bV[16];
    #pragma unroll
    for (int j = 0; j < 16; ++j) {
        const int l = lq + j;
        const float kv = kb_s[l][d];
        bF[j] = f2bf(kv * fws[l]);
        bS[j] = f2bf(kv * sws[l]);
        bV[j] = f2bf(vb_s[l][d]);
    }
    const size_t base = ((size_t)bh * DK_ + d) * L_ + l0 + lq;
    *(uint4*)(kfT + base) = *(const uint4*)&bF[0];
    *(uint4*)(kfT + base + 8) = *(const uint4*)&bF[8];
    *(uint4*)(ksT + base) = *(const uint4*)&bS[0];
    *(uint4*)(ksT + base + 8) = *(const uint4*)&bS[8];
    *(uint4*)(vT + base) = *(const uint4*)&bV[0];
    *(uint4*)(vT + base + 8) = *(const uint4*)&bV[8];
}

// ---------------------------------------------------------------------------
// M_fast/M_slow via MFMA; fp32 atomicAdd epilogue.
// ---------------------------------------------------------------------------
__global__ __launch_bounds__(256) void mstate_mfma_kernel(
    const unsigned short* __restrict__ kfT, const unsigned short* __restrict__ ksT,
    const unsigned short* __restrict__ vT,
    float* __restrict__ Mf, float* __restrict__ Ms)
{
    __shared__ unsigned short kf_s[64 * 32];
    __shared__ unsigned short ks_s[64 * 32];
    __shared__ unsigned short v_s[64 * 32];
    const int bh = blockIdx.x;
    const int seg = blockIdx.y;
    const int t = threadIdx.x, wv = t >> 6, lane = t & 63;
    const int q = lane >> 4, ml = lane & 15;
    const int wm = (wv >> 1) * 32, wn = (wv & 1) * 32;
    const size_t hb = (size_t)bh * DK_ * L_;
    const size_t grow = hb + (size_t)(wv * 16 + (lane >> 2)) * L_ + (lane & 3) * 8;
    f32x4 aF[2][2] = {}, aS[2][2] = {};
    for (int l0 = seg * 256; l0 < seg * 256 + 256; l0 += 32) {
        __syncthreads();
        gl_lds16(kfT + grow + l0, &kf_s[wv * 512]);
        gl_lds16(ksT + grow + l0, &ks_s[wv * 512]);
        gl_lds16(vT  + grow + l0, &v_s[wv * 512]);
        __syncthreads();
        bf16x8 fa[2], sa[2], vb[2];
        #pragma unroll
        for (int i = 0; i < 2; ++i) {
            fa[i] = *(const bf16x8*)&kf_s[(wm + i * 16 + ml) * 32 + q * 8];
            sa[i] = *(const bf16x8*)&ks_s[(wm + i * 16 + ml) * 32 + q * 8];
            vb[i] = *(const bf16x8*)&v_s[(wn + i * 16 + ml) * 32 + q * 8];
        }
        #pragma unroll
        for (int i = 0; i < 2; ++i)
            #pragma unroll
            for (int j = 0; j < 2; ++j) {
                aF[i][j] = __builtin_amdgcn_mfma_f32_16x16x32_bf16(fa[i], vb[j], aF[i][j], 0, 0, 0);
                aS[i][j] = __builtin_amdgcn_mfma_f32_16x16x32_bf16(sa[i], vb[j], aS[i][j], 0, 0, 0);
            }
    }
    #pragma unroll
    for (int i = 0; i < 2; ++i)
        #pragma unroll
        for (int j = 0; j < 2; ++j)
            #pragma unroll
            for (int r = 0; r < 4; ++r) {
                const int d = wm + i * 16 + q * 4 + r;
                const int e = wn + j * 16 + ml;
                atomicAdd(&Mf[(size_t)bh * (DK_ * DK_) + d * DK_ + e], aF[i][j][r]);
                atomicAdd(&Ms[(size_t)bh * (DK_ * DK_) + d * DK_ + e], aS[i][j][r]);
            }
}

// ---------------------------------------------------------------------------
// MtFS[bh][128][64] bf16: rows 0-63 = (Mf/dF)^T (row e, col d), 64-127 = (Ms/dS)^T
// ---------------------------------------------------------------------------
__global__ __launch_bounds__(256) void mprep_kernel(
    const float* __restrict__ Mf, const float* __restrict__ Ms,
    const float* __restrict__ denom, unsigned short* __restrict__ MtFS)
{
    __shared__ float mt[64][65];
    const int bh = blockIdx.x;
    const int t = threadIdx.x;
    const int r = t >> 2, c0 = (t & 3) * 16;
    #pragma unroll
    for (int s = 0; s < 2; ++s) {
        const float* M = (s == 0 ? Mf : Ms) + (size_t)bh * (DK_ * DK_);
        const float dn = denom[bh * 2 + s];
        __syncthreads();
        #pragma unroll
        for (int u = 0; u < 4; ++u) {
            float4 v = *(const float4*)&M[r * DK_ + c0 + u * 4];
            mt[r][c0 + u * 4 + 0] = v.x; mt[r][c0 + u * 4 + 1] = v.y;
            mt[r][c0 + u * 4 + 2] = v.z; mt[r][c0 + u * 4 + 3] = v.w;
        }
        __syncthreads();
        __align__(16) unsigned short ob[16];
        #pragma unroll
        for (int j = 0; j < 16; ++j) ob[j] = f2bf(mt[c0 + j][r] / dn);
        unsigned short* dst = MtFS + ((size_t)bh * 128 + s * 64 + r) * 64 + c0;
        *(uint4*)dst = *(const uint4*)&ob[0];
        *(uint4*)(dst + 8) = *(const uint4*)&ob[8];
    }
}

// ---------------------------------------------------------------------------
// o via MFMA: per block 128 tokens x 64 e, both states, alpha-mix epilogue.
// A = qb[l][d] (bf16), B = MtFS[e'][d] (bf16, denom folded). K=64.
// ---------------------------------------------------------------------------
__global__ __launch_bounds__(256) void o_mfma_kernel(
    const unsigned short* __restrict__ qb, const unsigned short* __restrict__ MtFS,
    const float* __restrict__ alphaA, unsigned short* __restrict__ Ob)
{
    __shared__ unsigned short As[128 * 72];   // q tile, padded rows
    __shared__ unsigned short Bs[128 * 72];   // MtFS tile, padded rows
    __shared__ float al[128];
    const int bh = blockIdx.x, lb = blockIdx.y;
    const int b = bh >> 4, h = bh & 15;
    const int t = threadIdx.x, wv = t >> 6, lane = t & 63;
    const int q = lane >> 4, ml = lane & 15;
    const int l0 = lb * 128;
    const int r0 = b * L_ + l0;
    // stage A and B: 1024 16B-chunks each; thread t covers chunk t + c*256
    #pragma unroll
    for (int c = 0; c < 4; ++c) {
        const int id = t + c * 256;
        const int row = id >> 3, ko = (id & 7) * 8;
        *(uint4*)&As[row * 72 + ko] =
            *(const uint4*)(qb + (size_t)(r0 + row) * D_ + h * DK_ + ko);
        *(uint4*)&Bs[row * 72 + ko] =
            *(const uint4*)(MtFS + ((size_t)bh * 128 + row) * 64 + ko);
    }
    if (t < 128) al[t] = alphaA[(size_t)bh * L_ + l0 + t];
    __syncthreads();
    const int wm = wv * 32;
    f32x4 acc[2][2][4] = {};   // [state][m][n]
    #pragma unroll
    for (int kk = 0; kk < 2; ++kk) {
        bf16x8 af[2];
        #pragma unroll
        for (int m = 0; m < 2; ++m)
            af[m] = *(const bf16x8*)&As[(wm + m * 16 + ml) * 72 + kk * 32 + q * 8];
        #pragma unroll
        for (int s = 0; s < 2; ++s)
            #pragma unroll
            for (int n = 0; n < 4; ++n) {
                bf16x8 bf = *(const bf16x8*)&Bs[(s * 64 + n * 16 + ml) * 72 + kk * 32 + q * 8];
                #pragma unroll
                for (int m = 0; m < 2; ++m)
                    acc[s][m][n] = __builtin_amdgcn_mfma_f32_16x16x32_bf16(af[m], bf, acc[s][m][n], 0, 0, 0);
            }
    }
    __syncthreads();
    // mix + repack (reuse Bs as C tile [128][64] bf16)
    unsigned short* Cs = Bs;
    #pragma unroll
    for (int m = 0; m < 2; ++m)
        #pragma unroll
        for (int r = 0; r < 4; ++r) {
            const int row = wm + m * 16 + q * 4 + r;
            const float a = al[row];
            #pragma unroll
            for (int n = 0; n < 4; ++n) {
                const float v = a * acc[0][m][n][r] + (1.f - a) * acc[1][m][n][r];
                Cs[row * 64 + n * 16 + ml] = f2bf(v);
            }
        }
    __syncthreads();
    // coalesced global write: thread -> (row = t>>1, 32-e half)
    const int row = t >> 1, eo = (t & 1) * 32;
    const uint4* src = (const uint4*)&Cs[row * 64 + eo];
    uint4* dst = (uint4*)(Ob + (size_t)(r0 + row) * D_ + h * DK_ + eo);
    #pragma unroll
    for (int u = 0; u < 4; ++u) dst[u] = src[u];
}

extern "C" void kernel_launch(void* const* d_in, const int* in_sizes, int n_in,
                              void* d_out, int out_size, void* d_ws, size_t ws_size,
                              hipStream_t stream)
{
    const float* x    = (const float*)d_in[0];
    const float* Wq   = (const float*)d_in[1];
    const float* Wk   = (const float*)d_in[2];
    const float* Wv   = (const float*)d_in[3];
    const float* Wb   = (const float*)d_in[4];
    const float* Wo   = (const float*)d_in[5];
    const float* Wfd  = (const float*)d_in[6];
    const float* bfd  = (const float*)d_in[7];
    const float* Wsd  = (const float*)d_in[8];
    const float* bsd  = (const float*)d_in[9];
    const float* Wtf1 = (const float*)d_in[10];
    const float* btf1 = (const float*)d_in[11];
    const float* Wtf2 = (const float*)d_in[12];
    const float* btf2 = (const float*)d_in[13];
    float* out        = (float*)d_out;

    char* w = (char*)d_ws;
    float* Q   = (float*)w;  w += (size_t)R_ * D_ * 4;
    float* Kb  = (float*)w;  w += (size_t)R_ * D_ * 4;
    float* Vb  = (float*)w;  w += (size_t)R_ * D_ * 4;
    unsigned short* xb  = (unsigned short*)w; w += (size_t)R_ * D_ * 2;  // reused as Ob
    unsigned short* qb  = (unsigned short*)w; w += (size_t)R_ * D_ * 2;
    unsigned short* Wtq = (unsigned short*)w; w += (size_t)D_ * D_ * 2;
    unsigned short* Wtk = (unsigned short*)w; w += (size_t)D_ * D_ * 2;
    unsigned short* Wtv = (unsigned short*)w; w += (size_t)D_ * D_ * 2;
    unsigned short* Wto = (unsigned short*)w; w += (size_t)D_ * D_ * 2;
    unsigned short* kfT = (unsigned short*)w; w += (size_t)32 * DK_ * L_ * 2;
    unsigned short* ksT = (unsigned short*)w; w += (size_t)32 * DK_ * L_ * 2;
    unsigned short* vT  = (unsigned short*)w; w += (size_t)32 * DK_ * L_ * 2;
    unsigned short* W3t = (unsigned short*)w; w += (size_t)48 * D_ * 2;
    unsigned short* MtFS= (unsigned short*)w; w += (size_t)32 * 128 * DK_ * 2;
    float* beta   = (float*)w; w += 32 * L_ * 4;
    float* fastd  = (float*)w; w += 32 * L_ * 4;
    float* slowd  = (float*)w; w += 32 * L_ * 4;
    float* fw     = (float*)w; w += 32 * L_ * 4;
    float* sw     = (float*)w; w += 32 * L_ * 4;
    float* alphaA = (float*)w; w += 32 * L_ * 4;
    float* Mf     = (float*)w; w += 32 * DK_ * DK_ * 4;
    float* Ms     = (float*)w; w += 32 * DK_ * DK_ * 4;
    float* denom  = (float*)w; w += 64 * 4;

    // prep: bf16 conversions / transposes
    cvt_bf16_kernel<<<R_ * D_ / 4 / 256, 256, 0, stream>>>(x, xb, R_ * D_ / 4);
    transpose_bf16_kernel<<<dim3(32, 32), 256, 0, stream>>>(Wq, Wtq);
    transpose_bf16_kernel<<<dim3(32, 32), 256, 0, stream>>>(Wk, Wtk);
    transpose_bf16_kernel<<<dim3(32, 32), 256, 0, stream>>>(Wv, Wtv);
    transpose_bf16_kernel<<<dim3(32, 32), 256, 0, stream>>>(Wo, Wto);
    proj_prep_kernel<<<48 * 1024 / 256, 256, 0, stream>>>(Wb, Wfd, Wsd, W3t);

    // small projections + scan
    proj_mfma_kernel<<<R_ / 64, 256, 0, stream>>>(xb, W3t, bfd, bsd, beta, fastd, slowd);
    scan_kernel<<<64, 256, 0, stream>>>(fastd, slowd, fw, sw, denom);

    // QKV projections
    gemm_bf16_kernel<<<dim3(D_ / 128, R_ / 128), 256, 0, stream>>>(xb, Wtq, Q,  R_, D_, D_);
    gemm_bf16_kernel<<<dim3(D_ / 128, R_ / 128), 256, 0, stream>>>(xb, Wtk, Kb, R_, D_, D_);
    gemm_bf16_kernel<<<dim3(D_ / 128, R_ / 128), 256, 0, stream>>>(xb, Wtv, Vb, R_, D_, D_);

    normflux_kernel<<<R_ * H_ / 4, 256, 0, stream>>>(Q, Kb, Vb, beta, Wtf1, btf1, Wtf2, btf2, alphaA, qb);
    tfx_kernel<<<dim3(H_, B_, L_ / 64), 256, 0, stream>>>(Kb, Vb, fw, sw, kfT, ksT, vT);
    (void)hipMemsetAsync(Mf, 0, 2 * 32 * DK_ * DK_ * sizeof(float), stream);
    mstate_mfma_kernel<<<dim3(32, 16), 256, 0, stream>>>(kfT, ksT, vT, Mf, Ms);
    mprep_kernel<<<32, 256, 0, stream>>>(Mf, Ms, denom, MtFS);
    o_mfma_kernel<<<dim3(32, 32), 256, 0, stream>>>(qb, MtFS, alphaA, xb);
    gemm_bf16_kernel<<<dim3(D_ / 128, R_ / 128), 256, 0, stream>>>(xb, Wto, out, R_, D_, D_);
}

// Round 7
// 321.060 us; speedup vs baseline: 5.9597x; 1.3123x over previous
//
#include <hip/hip_runtime.h>
#include <hip/hip_bf16.h>

#define B_ 2
#define L_ 4096
#define D_ 1024
#define H_ 16
#define DK_ 64
#define R_ (B_*L_)   // 8192 tokens
#define N3_ 3072     // fused QKV width

typedef __bf16 bf16x8 __attribute__((ext_vector_type(8)));
typedef float  f32x4  __attribute__((ext_vector_type(4)));

__device__ __forceinline__ float bf2f(unsigned short u) {
    return __uint_as_float(((unsigned int)u) << 16);
}
__device__ __forceinline__ unsigned short f2bf(float f) {   // RNE
    unsigned int u = __float_as_uint(f);
    return (unsigned short)((u + 0x7fffu + ((u >> 16) & 1u)) >> 16);
}

// async global->LDS, 16 B per lane; LDS dest = wave-uniform base + lane*16
__device__ __forceinline__ void gl_lds16(const void* g, void* l) {
    __builtin_amdgcn_global_load_lds(
        (const __attribute__((address_space(1))) void*)(uintptr_t)g,
        (__attribute__((address_space(3))) void*)(unsigned int)(uintptr_t)l,
        16, 0, 0);
}

// ---------------------------------------------------------------------------
// fp32 -> bf16 elementwise (vec4)
// ---------------------------------------------------------------------------
__global__ __launch_bounds__(256) void cvt_bf16_kernel(
    const float* __restrict__ src, unsigned short* __restrict__ dst, int n4)
{
    int i = blockIdx.x * 256 + threadIdx.x;
    if (i < n4) {
        float4 v = ((const float4*)src)[i];
        ushort4 o;
        o.x = f2bf(v.x); o.y = f2bf(v.y); o.z = f2bf(v.z); o.w = f2bf(v.w);
        ((ushort4*)dst)[i] = o;
    }
}

// ---------------------------------------------------------------------------
// fp32 W[K=1024][N=1024] -> bf16 Wt[N][K] (transpose + downcast), 32x32 tiles
// ---------------------------------------------------------------------------
__global__ __launch_bounds__(256) void transpose_bf16_kernel(
    const float* __restrict__ W, unsigned short* __restrict__ Wt)
{
    __shared__ unsigned short tile[32][33];
    const int bn = blockIdx.x * 32;
    const int bk = blockIdx.y * 32;
    const int tx = threadIdx.x & 31, ty = threadIdx.x >> 5;
    #pragma unroll
    for (int r = ty; r < 32; r += 8)
        tile[tx][r] = f2bf(W[(size_t)(bk + r) * D_ + bn + tx]);
    __syncthreads();
    #pragma unroll
    for (int r = ty; r < 32; r += 8)
        Wt[(size_t)(bn + r) * D_ + bk + tx] = tile[r][tx];
}

// ---------------------------------------------------------------------------
// bf16 MFMA GEMM (m97): C[M,N] = A[M,K] @ Bt[N,K]^T.  OUTBF: C bf16 else fp32.
// 128x128 tile, BK=32, 256 thr (4 waves 2x2), 4x4 16x16 frags per wave.
// ---------------------------------------------------------------------------
template <bool OUTBF>
__global__ __launch_bounds__(256) void gemm_bf16_kernel(
    const unsigned short* __restrict__ A,   // [M,K] bf16 bits
    const unsigned short* __restrict__ Bt,  // [N,K] bf16 bits
    void* __restrict__ Cp, int M, int N, int K)
{
    __shared__ unsigned short As[128 * 32];
    __shared__ unsigned short Bs[128 * 32];
    const int bm = blockIdx.y * 128;
    const int bn = blockIdx.x * 128;
    const int t = threadIdx.x;
    const int wv = t >> 6, lane = t & 63;
    const int q  = lane >> 4, ml = lane & 15;
    const int wm = (wv >> 1) * 64, wn = (wv & 1) * 64;
    const int row4 = t >> 2;
    const int kof  = (t & 3) * 8;
    f32x4 acc[4][4] = {};
    for (int k0 = 0; k0 < K; k0 += 32) {
        __syncthreads();
        #pragma unroll
        for (int i = 0; i < 2; ++i) {
            const unsigned short* ga = A  + (size_t)(bm + i * 64 + row4) * K + k0 + kof;
            const unsigned short* gb = Bt + (size_t)(bn + i * 64 + row4) * K + k0 + kof;
            gl_lds16(ga, &As[(i * 256 + wv * 64) * 8]);
            gl_lds16(gb, &Bs[(i * 256 + wv * 64) * 8]);
        }
        __syncthreads();
        bf16x8 af[4], bfr[4];
        #pragma unroll
        for (int i = 0; i < 4; ++i)
            af[i] = *(const bf16x8*)&As[(wm + i * 16 + ml) * 32 + q * 8];
        #pragma unroll
        for (int j = 0; j < 4; ++j)
            bfr[j] = *(const bf16x8*)&Bs[(wn + j * 16 + ml) * 32 + q * 8];
        #pragma unroll
        for (int i = 0; i < 4; ++i)
            #pragma unroll
            for (int j = 0; j < 4; ++j)
                acc[i][j] = __builtin_amdgcn_mfma_f32_16x16x32_bf16(af[i], bfr[j], acc[i][j], 0, 0, 0);
    }
    #pragma unroll
    for (int i = 0; i < 4; ++i) {
        #pragma unroll
        for (int r = 0; r < 4; ++r) {
            const int row = bm + wm + i * 16 + q * 4 + r;
            if constexpr (OUTBF) {
                unsigned short* cp = (unsigned short*)Cp + (size_t)row * N + bn + wn + ml;
                #pragma unroll
                for (int j = 0; j < 4; ++j) cp[j * 16] = f2bf(acc[i][j][r]);
            } else {
                float* cp = (float*)Cp + (size_t)row * N + bn + wn + ml;
                #pragma unroll
                for (int j = 0; j < 4; ++j) cp[j * 16] = acc[i][j][r];
            }
        }
    }
}

// ---------------------------------------------------------------------------
// W3t[48][1024] bf16: rows 0-15 = Wb^T, 16-31 = Wfd^T, 32-47 = Wsd^T
// ---------------------------------------------------------------------------
__global__ __launch_bounds__(256) void proj_prep_kernel(
    const float* __restrict__ Wb, const float* __restrict__ Wfd,
    const float* __restrict__ Wsd, unsigned short* __restrict__ W3t)
{
    int i = blockIdx.x * 256 + threadIdx.x;   // 48*1024
    int c = i >> 10, k = i & 1023;
    const float* W = c < 16 ? Wb : (c < 32 ? Wfd : Wsd);
    W3t[i] = f2bf(W[k * H_ + (c & 15)]);
}

// ---------------------------------------------------------------------------
// Wtf1t[32][64] bf16 from Wtf1[64][32] fp32
// ---------------------------------------------------------------------------
__global__ __launch_bounds__(256) void flux_prep_kernel(
    const float* __restrict__ Wtf1, unsigned short* __restrict__ Wtf1t)
{
    for (int i = threadIdx.x; i < 32 * 64; i += 256) {
        const int j = i >> 6, d = i & 63;
        Wtf1t[i] = f2bf(Wtf1[d * 32 + j]);
    }
}

// ---------------------------------------------------------------------------
// Small projections via MFMA: C[8192 x 48] = xb @ W3t^T; sigmoid(+bias).
// ---------------------------------------------------------------------------
__global__ __launch_bounds__(256) void proj_mfma_kernel(
    const unsigned short* __restrict__ xb, const unsigned short* __restrict__ W3t,
    const float* __restrict__ bfd, const float* __restrict__ bsd,
    float* __restrict__ beta, float* __restrict__ fastd, float* __restrict__ slowd)
{
    __shared__ unsigned short xs[64 * 32];
    __shared__ unsigned short wsh[48 * 32];
    const int t = threadIdx.x, wv = t >> 6, lane = t & 63;
    const int q = lane >> 4, ml = lane & 15;
    const int r0 = blockIdx.x * 64;
    f32x4 acc[3] = {};
    for (int k0 = 0; k0 < D_; k0 += 32) {
        __syncthreads();
        gl_lds16(xb + (size_t)(r0 + wv * 16 + (lane >> 2)) * D_ + k0 + (lane & 3) * 8,
                 &xs[wv * 512]);
        if (wv < 3)
            gl_lds16(W3t + (size_t)(wv * 16 + (lane >> 2)) * D_ + k0 + (lane & 3) * 8,
                     &wsh[wv * 512]);
        __syncthreads();
        bf16x8 af = *(const bf16x8*)&xs[(wv * 16 + ml) * 32 + q * 8];
        #pragma unroll
        for (int j = 0; j < 3; ++j) {
            bf16x8 bfr = *(const bf16x8*)&wsh[(j * 16 + ml) * 32 + q * 8];
            acc[j] = __builtin_amdgcn_mfma_f32_16x16x32_bf16(af, bfr, acc[j], 0, 0, 0);
        }
    }
    #pragma unroll
    for (int j = 0; j < 3; ++j) {
        #pragma unroll
        for (int r = 0; r < 4; ++r) {
            const int rg = r0 + wv * 16 + q * 4 + r;
            float v = acc[j][r];
            if (j == 1) v += bfd[ml];
            if (j == 2) v += bsd[ml];
            const float sg = 1.f / (1.f + expf(-v));
            const int b = rg >> 12, l = rg & (L_ - 1);
            float* dst = j == 0 ? beta : (j == 1 ? fastd : slowd);
            dst[(size_t)(b * H_ + ml) * L_ + l] = sg;
        }
    }
}

// ---------------------------------------------------------------------------
// Per-(b,h) scan of log(decay+1e-6); w = exp(total - cs); denom = sum(w)+1e-6.
// ---------------------------------------------------------------------------
__global__ __launch_bounds__(256) void scan_kernel(
    const float* __restrict__ fastd, const float* __restrict__ slowd,
    float* __restrict__ fw, float* __restrict__ sw, float* __restrict__ denom)
{
    __shared__ float part[256];
    const int bh = blockIdx.x >> 1;
    const int which = blockIdx.x & 1;
    const float* src = (which ? slowd : fastd) + (size_t)bh * L_;
    float* dst = (which ? sw : fw) + (size_t)bh * L_;
    const int t = threadIdx.x;
    float vals[16];
    float run = 0.f;
    #pragma unroll
    for (int i = 0; i < 16; ++i) {
        run += logf(src[t * 16 + i] + 1e-6f);
        vals[i] = run;
    }
    part[t] = run;
    __syncthreads();
    for (int off = 1; off < 256; off <<= 1) {
        float v = (t >= off) ? part[t - off] : 0.f;
        __syncthreads();
        part[t] += v;
        __syncthreads();
    }
    const float excl = part[t] - run;
    const float total = part[255];
    __syncthreads();
    float lsum = 0.f;
    #pragma unroll
    for (int i = 0; i < 16; ++i) {
        float w = expf(total - (vals[i] + excl));
        dst[t * 16 + i] = w;
        lsum += w;
    }
    part[t] = lsum;
    __syncthreads();
    for (int off = 128; off > 0; off >>= 1) {
        if (t < off) part[t] += part[t + off];
        __syncthreads();
    }
    if (t == 0) denom[bh * 2 + which] = part[0] + 1e-6f;
}

// ---------------------------------------------------------------------------
// ktv: per (h, b, 64-l chunk): k-norm + beta scale; writes
//   kbb[bh*L+l][d] bf16 (k_beta, rows)  and  kfT/ksT/vT[bh*64+d][l] bf16.
// Sources: QKVb k-slice (cols 1024..2047), v-slice (2048..3071), beta, fw, sw.
// ---------------------------------------------------------------------------
__global__ __launch_bounds__(256) void ktv_kernel(
    const unsigned short* __restrict__ QKVb,
    const float* __restrict__ beta, const float* __restrict__ fw,
    const float* __restrict__ sw,
    unsigned short* __restrict__ kbb,
    unsigned short* __restrict__ kfT, unsigned short* __restrict__ ksT,
    unsigned short* __restrict__ vT)
{
    __shared__ float kb_s[64][65];
    __shared__ float vb_s[64][65];
    __shared__ float ps[64][4];
    __shared__ float scl[64], bl[64], fws[64], sws[64];
    const int h = blockIdx.x, b = blockIdx.y, lc = blockIdx.z;
    const int l0 = lc * 64;
    const int bh = b * H_ + h;
    const int t = threadIdx.x;
    const int ll = t >> 2, dq = (t & 3) * 16;
    {
        const size_t rowb = (size_t)(b * L_ + l0 + ll) * N3_ + h * DK_ + dq;
        float s = 0.f;
        #pragma unroll
        for (int u = 0; u < 2; ++u) {
            ushort4 kv = *(const ushort4*)(QKVb + rowb + 1024 + u * 4);
            ushort4 k2 = *(const ushort4*)(QKVb + rowb + 1024 + 8 + u * 4);
            ushort4 vv = *(const ushort4*)(QKVb + rowb + 2048 + u * 4);
            ushort4 v2 = *(const ushort4*)(QKVb + rowb + 2048 + 8 + u * 4);
            float k0f = bf2f(kv.x), k1f = bf2f(kv.y), k2f = bf2f(kv.z), k3f = bf2f(kv.w);
            float k4f = bf2f(k2.x), k5f = bf2f(k2.y), k6f = bf2f(k2.z), k7f = bf2f(k2.w);
            kb_s[ll][dq + u * 4 + 0] = k0f; kb_s[ll][dq + u * 4 + 1] = k1f;
            kb_s[ll][dq + u * 4 + 2] = k2f; kb_s[ll][dq + u * 4 + 3] = k3f;
            kb_s[ll][dq + 8 + u * 4 + 0] = k4f; kb_s[ll][dq + 8 + u * 4 + 1] = k5f;
            kb_s[ll][dq + 8 + u * 4 + 2] = k6f; kb_s[ll][dq + 8 + u * 4 + 3] = k7f;
            s += k0f * k0f + k1f * k1f + k2f * k2f + k3f * k3f;
            s += k4f * k4f + k5f * k5f + k6f * k6f + k7f * k7f;
            vb_s[ll][dq + u * 4 + 0] = bf2f(vv.x); vb_s[ll][dq + u * 4 + 1] = bf2f(vv.y);
            vb_s[ll][dq + u * 4 + 2] = bf2f(vv.z); vb_s[ll][dq + u * 4 + 3] = bf2f(vv.w);
            vb_s[ll][dq + 8 + u * 4 + 0] = bf2f(v2.x); vb_s[ll][dq + 8 + u * 4 + 1] = bf2f(v2.y);
            vb_s[ll][dq + 8 + u * 4 + 2] = bf2f(v2.z); vb_s[ll][dq + 8 + u * 4 + 3] = bf2f(v2.w);
        }
        ps[ll][t & 3] = s;
        if (t < 64) {
            bl[t]  = beta[(size_t)bh * L_ + l0 + t];
            fws[t] = fw[(size_t)bh * L_ + l0 + t];
            sws[t] = sw[(size_t)bh * L_ + l0 + t];
        }
    }
    __syncthreads();
    if (t < 64) {
        const float n = sqrtf(ps[t][0] + ps[t][1] + ps[t][2] + ps[t][3]);
        scl[t] = bl[t] / fmaxf(n, 1e-12f);
    }
    __syncthreads();
    // kbb rows (k_beta)
    {
        __align__(16) unsigned short ob[16];
        const float s = scl[ll];
        #pragma unroll
        for (int j = 0; j < 16; ++j) ob[j] = f2bf(kb_s[ll][dq + j] * s);
        unsigned short* dst = kbb + ((size_t)bh * L_ + l0 + ll) * DK_ + dq;
        *(uint4*)dst = *(const uint4*)&ob[0];
        *(uint4*)(dst + 8) = *(const uint4*)&ob[8];
    }
    // transposed decay-scaled
    {
        const int d = t >> 2, lq = (t & 3) * 16;
        __align__(16) unsigned short bF[16], bS[16], bV[16];
        #pragma unroll
        for (int j = 0; j < 16; ++j) {
            const int l = lq + j;
            const float kb = kb_s[l][d] * scl[l];
            bF[j] = f2bf(kb * fws[l]);
            bS[j] = f2bf(kb * sws[l]);
            bV[j] = f2bf(vb_s[l][d] * bl[l]);
        }
        const size_t base = ((size_t)bh * DK_ + d) * L_ + l0 + lq;
        *(uint4*)(kfT + base) = *(const uint4*)&bF[0];
        *(uint4*)(kfT + base + 8) = *(const uint4*)&bF[8];
        *(uint4*)(ksT + base) = *(const uint4*)&bS[0];
        *(uint4*)(ksT + base + 8) = *(const uint4*)&bS[8];
        *(uint4*)(vT + base) = *(const uint4*)&bV[0];
        *(uint4*)(vT + base + 8) = *(const uint4*)&bV[8];
    }
}

// ---------------------------------------------------------------------------
// flux_alpha: alpha[rh] from kbb rows via MFMA.
// hmid = silu(kb @ Wtf1 + btf1); tf = clip(sigmoid(hmid @ Wtf2 + btf2));
// alpha = 0.5 + 0.3*tf.   128 rows/block, N=32, K=64.
// ---------------------------------------------------------------------------
__global__ __launch_bounds__(256) void flux_alpha_kernel(
    const unsigned short* __restrict__ kbb, const unsigned short* __restrict__ Wtf1t,
    const float* __restrict__ btf1, const float* __restrict__ Wtf2,
    const float* __restrict__ btf2, float* __restrict__ alphaA)
{
    __shared__ unsigned short As[128 * 72];
    __shared__ unsigned short Bs[32 * 72];
    const int t = threadIdx.x, wv = t >> 6, lane = t & 63;
    const int q = lane >> 4, ml = lane & 15;
    const size_t rh0 = (size_t)blockIdx.x * 128;
    #pragma unroll
    for (int c = 0; c < 4; ++c) {
        const int id = t + c * 256;
        const int row = id >> 3, ko = (id & 7) * 8;
        *(uint4*)&As[row * 72 + ko] = *(const uint4*)(kbb + (rh0 + row) * DK_ + ko);
    }
    {
        const int row = t >> 3, ko = (t & 7) * 8;   // 32 rows x 8 chunks
        if (row < 32)
            *(uint4*)&Bs[row * 72 + ko] = *(const uint4*)(Wtf1t + row * DK_ + ko);
    }
    __syncthreads();
    const int wm = wv * 32;
    f32x4 acc[2][2] = {};
    #pragma unroll
    for (int kk = 0; kk < 2; ++kk) {
        bf16x8 af[2];
        #pragma unroll
        for (int m = 0; m < 2; ++m)
            af[m] = *(const bf16x8*)&As[(wm + m * 16 + ml) * 72 + kk * 32 + q * 8];
        #pragma unroll
        for (int n = 0; n < 2; ++n) {
            bf16x8 bf = *(const bf16x8*)&Bs[(n * 16 + ml) * 72 + kk * 32 + q * 8];
            #pragma unroll
            for (int m = 0; m < 2; ++m)
                acc[m][n] = __builtin_amdgcn_mfma_f32_16x16x32_bf16(af[m], bf, acc[m][n], 0, 0, 0);
        }
    }
    const float bt2 = btf2[0];
    #pragma unroll
    for (int m = 0; m < 2; ++m) {
        #pragma unroll
        for (int r = 0; r < 4; ++r) {
            float v = 0.f;
            #pragma unroll
            for (int n = 0; n < 2; ++n) {
                const int col = n * 16 + ml;
                const float hmid = acc[m][n][r] + btf1[col];
                const float sil = hmid / (1.f + expf(-hmid));
                v += sil * Wtf2[col];
            }
            v += __shfl_xor(v, 1, 64);
            v += __shfl_xor(v, 2, 64);
            v += __shfl_xor(v, 4, 64);
            v += __shfl_xor(v, 8, 64);
            if (ml == 0) {
                float tf = 1.f / (1.f + expf(-(v + bt2)));
                tf = fminf(fmaxf(tf, 0.01f), 0.99f);
                const int row = wm + m * 16 + q * 4 + r;
                alphaA[rh0 + row] = 0.5f + 0.3f * tf;
            }
        }
    }
}

// ---------------------------------------------------------------------------
// M_fast/M_slow via MFMA; fp32 atomicAdd epilogue.
// ---------------------------------------------------------------------------
__global__ __launch_bounds__(256) void mstate_mfma_kernel(
    const unsigned short* __restrict__ kfT, const unsigned short* __restrict__ ksT,
    const unsigned short* __restrict__ vT,
    float* __restrict__ Mf, float* __restrict__ Ms)
{
    __shared__ unsigned short kf_s[64 * 32];
    __shared__ unsigned short ks_s[64 * 32];
    __shared__ unsigned short v_s[64 * 32];
    const int bh = blockIdx.x;
    const int seg = blockIdx.y;
    const int t = threadIdx.x, wv = t >> 6, lane = t & 63;
    const int q = lane >> 4, ml = lane & 15;
    const int wm = (wv >> 1) * 32, wn = (wv & 1) * 32;
    const size_t hb = (size_t)bh * DK_ * L_;
    const size_t grow = hb + (size_t)(wv * 16 + (lane >> 2)) * L_ + (lane & 3) * 8;
    f32x4 aF[2][2] = {}, aS[2][2] = {};
    for (int l0 = seg * 256; l0 < seg * 256 + 256; l0 += 32) {
        __syncthreads();
        gl_lds16(kfT + grow + l0, &kf_s[wv * 512]);
        gl_lds16(ksT + grow + l0, &ks_s[wv * 512]);
        gl_lds16(vT  + grow + l0, &v_s[wv * 512]);
        __syncthreads();
        bf16x8 fa[2], sa[2], vb[2];
        #pragma unroll
        for (int i = 0; i < 2; ++i) {
            fa[i] = *(const bf16x8*)&kf_s[(wm + i * 16 + ml) * 32 + q * 8];
            sa[i] = *(const bf16x8*)&ks_s[(wm + i * 16 + ml) * 32 + q * 8];
            vb[i] = *(const bf16x8*)&v_s[(wn + i * 16 + ml) * 32 + q * 8];
        }
        #pragma unroll
        for (int i = 0; i < 2; ++i)
            #pragma unroll
            for (int j = 0; j < 2; ++j) {
                aF[i][j] = __builtin_amdgcn_mfma_f32_16x16x32_bf16(fa[i], vb[j], aF[i][j], 0, 0, 0);
                aS[i][j] = __builtin_amdgcn_mfma_f32_16x16x32_bf16(sa[i], vb[j], aS[i][j], 0, 0, 0);
            }
    }
    #pragma unroll
    for (int i = 0; i < 2; ++i)
        #pragma unroll
        for (int j = 0; j < 2; ++j)
            #pragma unroll
            for (int r = 0; r < 4; ++r) {
                const int d = wm + i * 16 + q * 4 + r;
                const int e = wn + j * 16 + ml;
                atomicAdd(&Mf[(size_t)bh * (DK_ * DK_) + d * DK_ + e], aF[i][j][r]);
                atomicAdd(&Ms[(size_t)bh * (DK_ * DK_) + d * DK_ + e], aS[i][j][r]);
            }
}

// ---------------------------------------------------------------------------
// MtFS[bh][128][64] bf16: rows 0-63 = (Mf/dF)^T, 64-127 = (Ms/dS)^T
// ---------------------------------------------------------------------------
__global__ __launch_bounds__(256) void mprep_kernel(
    const float* __restrict__ Mf, const float* __restrict__ Ms,
    const float* __restrict__ denom, unsigned short* __restrict__ MtFS)
{
    __shared__ float mt[64][65];
    const int bh = blockIdx.x;
    const int t = threadIdx.x;
    const int r = t >> 2, c0 = (t & 3) * 16;
    #pragma unroll
    for (int s = 0; s < 2; ++s) {
        const float* M = (s == 0 ? Mf : Ms) + (size_t)bh * (DK_ * DK_);
        const float dn = denom[bh * 2 + s];
        __syncthreads();
        #pragma unroll
        for (int u = 0; u < 4; ++u) {
            float4 v = *(const float4*)&M[r * DK_ + c0 + u * 4];
            mt[r][c0 + u * 4 + 0] = v.x; mt[r][c0 + u * 4 + 1] = v.y;
            mt[r][c0 + u * 4 + 2] = v.z; mt[r][c0 + u * 4 + 3] = v.w;
        }
        __syncthreads();
        __align__(16) unsigned short ob[16];
        #pragma unroll
        for (int j = 0; j < 16; ++j) ob[j] = f2bf(mt[c0 + j][r] / dn);
        unsigned short* dst = MtFS + ((size_t)bh * 128 + s * 64 + r) * 64 + c0;
        *(uint4*)dst = *(const uint4*)&ob[0];
        *(uint4*)(dst + 8) = *(const uint4*)&ob[8];
    }
}

// ---------------------------------------------------------------------------
// o via MFMA: 128 tokens x 64 e per block; raw q from QKVb; q-norm folded into
// epilogue ((q/||q||)@M = (q@M)/||q||); alpha-mix; bf16 out.
// ---------------------------------------------------------------------------
__global__ __launch_bounds__(256) void o_mfma_kernel(
    const unsigned short* __restrict__ QKVb, const unsigned short* __restrict__ MtFS,
    const float* __restrict__ alphaA, unsigned short* __restrict__ Ob)
{
    __shared__ unsigned short As[128 * 72];   // raw q tile
    __shared__ unsigned short Bs[128 * 72];   // MtFS tile
    __shared__ float al[128];
    __shared__ float qs2[128][2];
    __shared__ float nrm[128];
    const int bh = blockIdx.x, lb = blockIdx.y;
    const int b = bh >> 4, h = bh & 15;
    const int t = threadIdx.x, wv = t >> 6, lane = t & 63;
    const int q = lane >> 4, ml = lane & 15;
    const int l0 = lb * 128;
    const int r0 = b * L_ + l0;
    #pragma unroll
    for (int c = 0; c < 4; ++c) {
        const int id = t + c * 256;
        const int row = id >> 3, ko = (id & 7) * 8;
        *(uint4*)&As[row * 72 + ko] =
            *(const uint4*)(QKVb + (size_t)(r0 + row) * N3_ + h * DK_ + ko);
        *(uint4*)&Bs[row * 72 + ko] =
            *(const uint4*)(MtFS + ((size_t)bh * 128 + row) * 64 + ko);
    }
    if (t < 128) al[t] = alphaA[(size_t)bh * L_ + l0 + t];
    __syncthreads();
    // row sumsq of q (each thread: 32 elems of one row-half)
    {
        const int row = t >> 1, half = (t & 1) * 32;
        float s = 0.f;
        #pragma unroll
        for (int j = 0; j < 32; ++j) {
            const float v = bf2f(As[row * 72 + half + j]);
            s += v * v;
        }
        qs2[row][t & 1] = s;
    }
    const int wm = wv * 32;
    f32x4 acc[2][2][4] = {};   // [state][m][n]
    #pragma unroll
    for (int kk = 0; kk < 2; ++kk) {
        bf16x8 af[2];
        #pragma unroll
        for (int m = 0; m < 2; ++m)
            af[m] = *(const bf16x8*)&As[(wm + m * 16 + ml) * 72 + kk * 32 + q * 8];
        #pragma unroll
        for (int s = 0; s < 2; ++s)
            #pragma unroll
            for (int n = 0; n < 4; ++n) {
                bf16x8 bf = *(const bf16x8*)&Bs[(s * 64 + n * 16 + ml) * 72 + kk * 32 + q * 8];
                #pragma unroll
                for (int m = 0; m < 2; ++m)
                    acc[s][m][n] = __builtin_amdgcn_mfma_f32_16x16x32_bf16(af[m], bf, acc[s][m][n], 0, 0, 0);
            }
    }
    __syncthreads();
    if (t < 128) nrm[t] = 1.f / fmaxf(sqrtf(qs2[t][0] + qs2[t][1]), 1e-12f);
    __syncthreads();
    // mix + repack (reuse Bs as C tile [128][64] bf16)
    unsigned short* Cs = Bs;
    #pragma unroll
    for (int m = 0; m < 2; ++m)
        #pragma unroll
        for (int r = 0; r < 4; ++r) {
            const int row = wm + m * 16 + q * 4 + r;
            const float a = al[row], sc = nrm[row];
            #pragma unroll
            for (int n = 0; n < 4; ++n) {
                const float v = sc * (a * acc[0][m][n][r] + (1.f - a) * acc[1][m][n][r]);
                Cs[row * 64 + n * 16 + ml] = f2bf(v);
            }
        }
    __syncthreads();
    const int row = t >> 1, eo = (t & 1) * 32;
    const uint4* src = (const uint4*)&Cs[row * 64 + eo];
    uint4* dst = (uint4*)(Ob + (size_t)(r0 + row) * D_ + h * DK_ + eo);
    #pragma unroll
    for (int u = 0; u < 4; ++u) dst[u] = src[u];
}

extern "C" void kernel_launch(void* const* d_in, const int* in_sizes, int n_in,
                              void* d_out, int out_size, void* d_ws, size_t ws_size,
                              hipStream_t stream)
{
    const float* x    = (const float*)d_in[0];
    const float* Wq   = (const float*)d_in[1];
    const float* Wk   = (const float*)d_in[2];
    const float* Wv   = (const float*)d_in[3];
    const float* Wb   = (const float*)d_in[4];
    const float* Wo   = (const float*)d_in[5];
    const float* Wfd  = (const float*)d_in[6];
    const float* bfd  = (const float*)d_in[7];
    const float* Wsd  = (const float*)d_in[8];
    const float* bsd  = (const float*)d_in[9];
    const float* Wtf1 = (const float*)d_in[10];
    const float* btf1 = (const float*)d_in[11];
    const float* Wtf2 = (const float*)d_in[12];
    const float* btf2 = (const float*)d_in[13];
    float* out        = (float*)d_out;

    char* w = (char*)d_ws;
    unsigned short* xb    = (unsigned short*)w; w += (size_t)R_ * D_ * 2;   // reused as Ob
    unsigned short* QKVb  = (unsigned short*)w; w += (size_t)R_ * N3_ * 2;
    unsigned short* Wtqkv = (unsigned short*)w; w += (size_t)3 * D_ * D_ * 2;
    unsigned short* Wto   = (unsigned short*)w; w += (size_t)D_ * D_ * 2;
    unsigned short* kbb   = (unsigned short*)w; w += (size_t)32 * L_ * DK_ * 2;
    unsigned short* kfT   = (unsigned short*)w; w += (size_t)32 * DK_ * L_ * 2;
    unsigned short* ksT   = (unsigned short*)w; w += (size_t)32 * DK_ * L_ * 2;
    unsigned short* vT    = (unsigned short*)w; w += (size_t)32 * DK_ * L_ * 2;
    unsigned short* W3t   = (unsigned short*)w; w += (size_t)48 * D_ * 2;
    unsigned short* Wtf1t = (unsigned short*)w; w += (size_t)32 * DK_ * 2;
    unsigned short* MtFS  = (unsigned short*)w; w += (size_t)32 * 128 * DK_ * 2;
    float* beta   = (float*)w; w += 32 * L_ * 4;
    float* fastd  = (float*)w; w += 32 * L_ * 4;
    float* slowd  = (float*)w; w += 32 * L_ * 4;
    float* fw     = (float*)w; w += 32 * L_ * 4;
    float* sw     = (float*)w; w += 32 * L_ * 4;
    float* alphaA = (float*)w; w += 32 * L_ * 4;
    float* Mf     = (float*)w; w += 32 * DK_ * DK_ * 4;
    float* Ms     = (float*)w; w += 32 * DK_ * DK_ * 4;
    float* denom  = (float*)w; w += 64 * 4;

    // prep
    cvt_bf16_kernel<<<R_ * D_ / 4 / 256, 256, 0, stream>>>(x, xb, R_ * D_ / 4);
    transpose_bf16_kernel<<<dim3(32, 32), 256, 0, stream>>>(Wq, Wtqkv);
    transpose_bf16_kernel<<<dim3(32, 32), 256, 0, stream>>>(Wk, Wtqkv + (size_t)D_ * D_);
    transpose_bf16_kernel<<<dim3(32, 32), 256, 0, stream>>>(Wv, Wtqkv + (size_t)2 * D_ * D_);
    transpose_bf16_kernel<<<dim3(32, 32), 256, 0, stream>>>(Wo, Wto);
    proj_prep_kernel<<<48 * 1024 / 256, 256, 0, stream>>>(Wb, Wfd, Wsd, W3t);
    flux_prep_kernel<<<1, 256, 0, stream>>>(Wtf1, Wtf1t);

    // small projections + scan
    proj_mfma_kernel<<<R_ / 64, 256, 0, stream>>>(xb, W3t, bfd, bsd, beta, fastd, slowd);
    scan_kernel<<<64, 256, 0, stream>>>(fastd, slowd, fw, sw, denom);

    // fused QKV projection (bf16 out)
    gemm_bf16_kernel<true><<<dim3(N3_ / 128, R_ / 128), 256, 0, stream>>>(
        xb, Wtqkv, QKVb, R_, N3_, D_);

    ktv_kernel<<<dim3(H_, B_, L_ / 64), 256, 0, stream>>>(
        QKVb, beta, fw, sw, kbb, kfT, ksT, vT);
    flux_alpha_kernel<<<(size_t)R_ * H_ / 128, 256, 0, stream>>>(
        kbb, Wtf1t, btf1, Wtf2, btf2, alphaA);
    (void)hipMemsetAsync(Mf, 0, 2 * 32 * DK_ * DK_ * sizeof(float), stream);
    mstate_mfma_kernel<<<dim3(32, 16), 256, 0, stream>>>(kfT, ksT, vT, Mf, Ms);
    mprep_kernel<<<32, 256, 0, stream>>>(Mf, Ms, denom, MtFS);
    o_mfma_kernel<<<dim3(32, 32), 256, 0, stream>>>(QKVb, MtFS, alphaA, xb);
    gemm_bf16_kernel<false><<<dim3(D_ / 128, R_ / 128), 256, 0, stream>>>(
        xb, Wto, out, R_, D_, D_);
}

// Round 8
// 297.349 us; speedup vs baseline: 6.4349x; 1.0797x over previous
//
#include <hip/hip_runtime.h>
#include <hip/hip_bf16.h>

#define B_ 2
#define L_ 4096
#define D_ 1024
#define H_ 16
#define DK_ 64
#define R_ (B_*L_)   // 8192 tokens
#define N3_ 3072     // fused QKV width

typedef __bf16 bf16x8 __attribute__((ext_vector_type(8)));
typedef float  f32x4  __attribute__((ext_vector_type(4)));

__device__ __forceinline__ float bf2f(unsigned short u) {
    return __uint_as_float(((unsigned int)u) << 16);
}
__device__ __forceinline__ unsigned short f2bf(float f) {   // RNE
    unsigned int u = __float_as_uint(f);
    return (unsigned short)((u + 0x7fffu + ((u >> 16) & 1u)) >> 16);
}

// async global->LDS, 16 B per lane; LDS dest = wave-uniform base + lane*16
__device__ __forceinline__ void gl_lds16(const void* g, void* l) {
    __builtin_amdgcn_global_load_lds(
        (const __attribute__((address_space(1))) void*)(uintptr_t)g,
        (__attribute__((address_space(3))) void*)(unsigned int)(uintptr_t)l,
        16, 0, 0);
}

// ---------------------------------------------------------------------------
// prep_all: one kernel for all input conversions.
//   bx in [0,8192)            : x fp32 -> xb bf16 (vec4)
//   bx in [8192,12288)        : W{q,k,v,o} [K][N] -> bf16 [N][K] 32x32 transpose
//   bx in [12288,12480)       : W3t[48][1024]  (Wb/Wfd/Wsd transposed)
//   bx == 12480               : Wtf1t[32][64]
// ---------------------------------------------------------------------------
__global__ __launch_bounds__(256) void prep_all_kernel(
    const float* __restrict__ x,
    const float* __restrict__ Wq, const float* __restrict__ Wk,
    const float* __restrict__ Wv, const float* __restrict__ Wo,
    const float* __restrict__ Wb, const float* __restrict__ Wfd,
    const float* __restrict__ Wsd, const float* __restrict__ Wtf1,
    unsigned short* __restrict__ xb, unsigned short* __restrict__ Wtqkv,
    unsigned short* __restrict__ Wto, unsigned short* __restrict__ W3t,
    unsigned short* __restrict__ Wtf1t)
{
    __shared__ unsigned short tile[32][33];
    const int bx = blockIdx.x, t = threadIdx.x;
    if (bx < 8192) {
        const int i = bx * 256 + t;
        float4 v = ((const float4*)x)[i];
        ushort4 o;
        o.x = f2bf(v.x); o.y = f2bf(v.y); o.z = f2bf(v.z); o.w = f2bf(v.w);
        ((ushort4*)xb)[i] = o;
    } else if (bx < 8192 + 4096) {
        const int id = bx - 8192;
        const int which = id >> 10, idx = id & 1023;
        const float* W = which == 0 ? Wq : (which == 1 ? Wk : (which == 2 ? Wv : Wo));
        unsigned short* Wt = which < 3 ? Wtqkv + (size_t)which * D_ * D_ : Wto;
        const int bn = (idx & 31) * 32, bk = (idx >> 5) * 32;
        const int tx = t & 31, ty = t >> 5;
        #pragma unroll
        for (int r = ty; r < 32; r += 8)
            tile[tx][r] = f2bf(W[(size_t)(bk + r) * D_ + bn + tx]);
        __syncthreads();
        #pragma unroll
        for (int r = ty; r < 32; r += 8)
            Wt[(size_t)(bn + r) * D_ + bk + tx] = tile[r][tx];
    } else if (bx < 8192 + 4096 + 192) {
        const int i = (bx - (8192 + 4096)) * 256 + t;
        const int c = i >> 10, k = i & 1023;
        const float* W = c < 16 ? Wb : (c < 32 ? Wfd : Wsd);
        W3t[i] = f2bf(W[k * H_ + (c & 15)]);
    } else {
        for (int i = t; i < 32 * 64; i += 256) {
            const int j = i >> 6, d = i & 63;
            Wtf1t[i] = f2bf(Wtf1[d * 32 + j]);
        }
    }
}

// ---------------------------------------------------------------------------
// bf16 MFMA GEMM (m97): C[M,N] = A[M,K] @ Bt[N,K]^T.  OUTBF: bf16 C with
// LDS-repacked coalesced uint4 stores; else fp32 dword stores.
// 128x128 tile, BK=32, 256 thr (4 waves 2x2), 4x4 16x16 frags per wave.
// ---------------------------------------------------------------------------
template <bool OUTBF>
__global__ __launch_bounds__(256) void gemm_bf16_kernel(
    const unsigned short* __restrict__ A,   // [M,K] bf16 bits
    const unsigned short* __restrict__ Bt,  // [N,K] bf16 bits
    void* __restrict__ Cp, int M, int N, int K)
{
    __shared__ unsigned short sh[2 * 128 * 32];   // As | Bs ; reused for C repack
    unsigned short* As = sh;
    unsigned short* Bs = sh + 128 * 32;
    const int bm = blockIdx.y * 128;
    const int bn = blockIdx.x * 128;
    const int t = threadIdx.x;
    const int wv = t >> 6, lane = t & 63;
    const int q  = lane >> 4, ml = lane & 15;
    const int wm = (wv >> 1) * 64, wn = (wv & 1) * 64;
    const int row4 = t >> 2;
    const int kof  = (t & 3) * 8;
    f32x4 acc[4][4] = {};
    for (int k0 = 0; k0 < K; k0 += 32) {
        __syncthreads();
        #pragma unroll
        for (int i = 0; i < 2; ++i) {
            const unsigned short* ga = A  + (size_t)(bm + i * 64 + row4) * K + k0 + kof;
            const unsigned short* gb = Bt + (size_t)(bn + i * 64 + row4) * K + k0 + kof;
            gl_lds16(ga, &As[(i * 256 + wv * 64) * 8]);
            gl_lds16(gb, &Bs[(i * 256 + wv * 64) * 8]);
        }
        __syncthreads();
        bf16x8 af[4], bfr[4];
        #pragma unroll
        for (int i = 0; i < 4; ++i)
            af[i] = *(const bf16x8*)&As[(wm + i * 16 + ml) * 32 + q * 8];
        #pragma unroll
        for (int j = 0; j < 4; ++j)
            bfr[j] = *(const bf16x8*)&Bs[(wn + j * 16 + ml) * 32 + q * 8];
        #pragma unroll
        for (int i = 0; i < 4; ++i)
            #pragma unroll
            for (int j = 0; j < 4; ++j)
                acc[i][j] = __builtin_amdgcn_mfma_f32_16x16x32_bf16(af[i], bfr[j], acc[i][j], 0, 0, 0);
    }
    if constexpr (OUTBF) {
        // repack through LDS in two 64-row chunks -> coalesced uint4 stores
        #pragma unroll
        for (int chunk = 0; chunk < 2; ++chunk) {
            __syncthreads();
            if ((wv >> 1) == chunk) {
                #pragma unroll
                for (int i = 0; i < 4; ++i)
                    #pragma unroll
                    for (int r = 0; r < 4; ++r) {
                        const int lr = i * 16 + q * 4 + r;
                        #pragma unroll
                        for (int j = 0; j < 4; ++j)
                            sh[lr * 128 + wn + j * 16 + ml] = f2bf(acc[i][j][r]);
                    }
            }
            __syncthreads();
            #pragma unroll
            for (int u = 0; u < 4; ++u) {
                const int id = t + u * 256;
                const int row = id >> 4, colc = (id & 15) * 8;
                *(uint4*)((unsigned short*)Cp + (size_t)(bm + chunk * 64 + row) * N + bn + colc)
                    = *(const uint4*)&sh[row * 128 + colc];
            }
        }
    } else {
        #pragma unroll
        for (int i = 0; i < 4; ++i) {
            #pragma unroll
            for (int r = 0; r < 4; ++r) {
                const int row = bm + wm + i * 16 + q * 4 + r;
                float* cp = (float*)Cp + (size_t)row * N + bn + wn + ml;
                #pragma unroll
                for (int j = 0; j < 4; ++j) cp[j * 16] = acc[i][j][r];
            }
        }
    }
}

// ---------------------------------------------------------------------------
// Small projections via MFMA: C[8192 x 48] = xb @ W3t^T; sigmoid(+bias).
// ---------------------------------------------------------------------------
__global__ __launch_bounds__(256) void proj_mfma_kernel(
    const unsigned short* __restrict__ xb, const unsigned short* __restrict__ W3t,
    const float* __restrict__ bfd, const float* __restrict__ bsd,
    float* __restrict__ beta, float* __restrict__ fastd, float* __restrict__ slowd)
{
    __shared__ unsigned short xs[64 * 32];
    __shared__ unsigned short wsh[48 * 32];
    const int t = threadIdx.x, wv = t >> 6, lane = t & 63;
    const int q = lane >> 4, ml = lane & 15;
    const int r0 = blockIdx.x * 64;
    f32x4 acc[3] = {};
    for (int k0 = 0; k0 < D_; k0 += 32) {
        __syncthreads();
        gl_lds16(xb + (size_t)(r0 + wv * 16 + (lane >> 2)) * D_ + k0 + (lane & 3) * 8,
                 &xs[wv * 512]);
        if (wv < 3)
            gl_lds16(W3t + (size_t)(wv * 16 + (lane >> 2)) * D_ + k0 + (lane & 3) * 8,
                     &wsh[wv * 512]);
        __syncthreads();
        bf16x8 af = *(const bf16x8*)&xs[(wv * 16 + ml) * 32 + q * 8];
        #pragma unroll
        for (int j = 0; j < 3; ++j) {
            bf16x8 bfr = *(const bf16x8*)&wsh[(j * 16 + ml) * 32 + q * 8];
            acc[j] = __builtin_amdgcn_mfma_f32_16x16x32_bf16(af, bfr, acc[j], 0, 0, 0);
        }
    }
    #pragma unroll
    for (int j = 0; j < 3; ++j) {
        #pragma unroll
        for (int r = 0; r < 4; ++r) {
            const int rg = r0 + wv * 16 + q * 4 + r;
            float v = acc[j][r];
            if (j == 1) v += bfd[ml];
            if (j == 2) v += bsd[ml];
            const float sg = 1.f / (1.f + expf(-v));
            const int b = rg >> 12, l = rg & (L_ - 1);
            float* dst = j == 0 ? beta : (j == 1 ? fastd : slowd);
            dst[(size_t)(b * H_ + ml) * L_ + l] = sg;
        }
    }
}

// ---------------------------------------------------------------------------
// Per-(b,h) scan of log(decay+1e-6); w = exp(total - cs); denom = sum(w)+1e-6.
// ---------------------------------------------------------------------------
__global__ __launch_bounds__(256) void scan_kernel(
    const float* __restrict__ fastd, const float* __restrict__ slowd,
    float* __restrict__ fw, float* __restrict__ sw, float* __restrict__ denom)
{
    __shared__ float part[256];
    const int bh = blockIdx.x >> 1;
    const int which = blockIdx.x & 1;
    const float* src = (which ? slowd : fastd) + (size_t)bh * L_;
    float* dst = (which ? sw : fw) + (size_t)bh * L_;
    const int t = threadIdx.x;
    float vals[16];
    float run = 0.f;
    #pragma unroll
    for (int i = 0; i < 16; ++i) {
        run += logf(src[t * 16 + i] + 1e-6f);
        vals[i] = run;
    }
    part[t] = run;
    __syncthreads();
    for (int off = 1; off < 256; off <<= 1) {
        float v = (t >= off) ? part[t - off] : 0.f;
        __syncthreads();
        part[t] += v;
        __syncthreads();
    }
    const float excl = part[t] - run;
    const float total = part[255];
    __syncthreads();
    float lsum = 0.f;
    #pragma unroll
    for (int i = 0; i < 16; ++i) {
        float w = expf(total - (vals[i] + excl));
        dst[t * 16 + i] = w;
        lsum += w;
    }
    part[t] = lsum;
    __syncthreads();
    for (int off = 128; off > 0; off >>= 1) {
        if (t < off) part[t] += part[t + off];
        __syncthreads();
    }
    if (t == 0) denom[bh * 2 + which] = part[0] + 1e-6f;
}

// ---------------------------------------------------------------------------
// ktv_flux: per (h, b, 64-l chunk):
//   k-norm + beta scale; writes kfT/ksT/vT[bh*64+d][l] bf16;
//   fused token-flux MLP (MFMA on in-LDS k_beta) -> alphaA.
// ---------------------------------------------------------------------------
__global__ __launch_bounds__(256) void ktv_flux_kernel(
    const unsigned short* __restrict__ QKVb,
    const float* __restrict__ beta, const float* __restrict__ fw,
    const float* __restrict__ sw,
    const unsigned short* __restrict__ Wtf1t, const float* __restrict__ btf1,
    const float* __restrict__ Wtf2, const float* __restrict__ btf2,
    unsigned short* __restrict__ kfT, unsigned short* __restrict__ ksT,
    unsigned short* __restrict__ vT, float* __restrict__ alphaA)
{
    __shared__ float kb_s[64][65];
    __shared__ float vb_s[64][65];
    __shared__ unsigned short kbt[64][72];   // k_beta bf16, MFMA A tile
    __shared__ unsigned short wtf[32][72];   // Wtf1t tile
    __shared__ float ps[64][4];
    __shared__ float scl[64], bl[64], fws[64], sws[64];
    __shared__ float b1s[32], w2s[32];
    const int h = blockIdx.x, b = blockIdx.y, lc = blockIdx.z;
    const int l0 = lc * 64;
    const int bh = b * H_ + h;
    const int t = threadIdx.x;
    const int wv = t >> 6, lane = t & 63;
    const int q = lane >> 4, ml = lane & 15;
    const int ll = t >> 2, dq = (t & 3) * 16;
    {
        const size_t rowb = (size_t)(b * L_ + l0 + ll) * N3_ + h * DK_ + dq;
        float s = 0.f;
        #pragma unroll
        for (int u = 0; u < 2; ++u) {
            ushort4 kv = *(const ushort4*)(QKVb + rowb + 1024 + u * 4);
            ushort4 k2 = *(const ushort4*)(QKVb + rowb + 1024 + 8 + u * 4);
            ushort4 vv = *(const ushort4*)(QKVb + rowb + 2048 + u * 4);
            ushort4 v2 = *(const ushort4*)(QKVb + rowb + 2048 + 8 + u * 4);
            float k0f = bf2f(kv.x), k1f = bf2f(kv.y), k2f = bf2f(kv.z), k3f = bf2f(kv.w);
            float k4f = bf2f(k2.x), k5f = bf2f(k2.y), k6f = bf2f(k2.z), k7f = bf2f(k2.w);
            kb_s[ll][dq + u * 4 + 0] = k0f; kb_s[ll][dq + u * 4 + 1] = k1f;
            kb_s[ll][dq + u * 4 + 2] = k2f; kb_s[ll][dq + u * 4 + 3] = k3f;
            kb_s[ll][dq + 8 + u * 4 + 0] = k4f; kb_s[ll][dq + 8 + u * 4 + 1] = k5f;
            kb_s[ll][dq + 8 + u * 4 + 2] = k6f; kb_s[ll][dq + 8 + u * 4 + 3] = k7f;
            s += k0f * k0f + k1f * k1f + k2f * k2f + k3f * k3f;
            s += k4f * k4f + k5f * k5f + k6f * k6f + k7f * k7f;
            vb_s[ll][dq + u * 4 + 0] = bf2f(vv.x); vb_s[ll][dq + u * 4 + 1] = bf2f(vv.y);
            vb_s[ll][dq + u * 4 + 2] = bf2f(vv.z); vb_s[ll][dq + u * 4 + 3] = bf2f(vv.w);
            vb_s[ll][dq + 8 + u * 4 + 0] = bf2f(v2.x); vb_s[ll][dq + 8 + u * 4 + 1] = bf2f(v2.y);
            vb_s[ll][dq + 8 + u * 4 + 2] = bf2f(v2.z); vb_s[ll][dq + 8 + u * 4 + 3] = bf2f(v2.w);
        }
        ps[ll][t & 3] = s;
        if (t < 64) {
            bl[t]  = beta[(size_t)bh * L_ + l0 + t];
            fws[t] = fw[(size_t)bh * L_ + l0 + t];
            sws[t] = sw[(size_t)bh * L_ + l0 + t];
        }
        {   // stage Wtf1t tile + biases
            const int row = t >> 3, ko = (t & 7) * 8;
            if (row < 32)
                *(uint4*)&wtf[row][ko] = *(const uint4*)(Wtf1t + row * DK_ + ko);
            if (t < 32) { b1s[t] = btf1[t]; w2s[t] = Wtf2[t]; }
        }
    }
    __syncthreads();
    if (t < 64) {
        const float n = sqrtf(ps[t][0] + ps[t][1] + ps[t][2] + ps[t][3]);
        scl[t] = bl[t] / fmaxf(n, 1e-12f);
    }
    __syncthreads();
    // k_beta bf16 tile (rows) for the flux MFMA
    {
        const float s = scl[ll];
        #pragma unroll
        for (int j = 0; j < 16; ++j) kbt[ll][dq + j] = f2bf(kb_s[ll][dq + j] * s);
    }
    // transposed decay-scaled global writes
    {
        const int d = t >> 2, lq = (t & 3) * 16;
        __align__(16) unsigned short bF[16], bS[16], bV[16];
        #pragma unroll
        for (int j = 0; j < 16; ++j) {
            const int l = lq + j;
            const float kb = kb_s[l][d] * scl[l];
            bF[j] = f2bf(kb * fws[l]);
            bS[j] = f2bf(kb * sws[l]);
            bV[j] = f2bf(vb_s[l][d] * bl[l]);
        }
        const size_t base = ((size_t)bh * DK_ + d) * L_ + l0 + lq;
        *(uint4*)(kfT + base) = *(const uint4*)&bF[0];
        *(uint4*)(kfT + base + 8) = *(const uint4*)&bF[8];
        *(uint4*)(ksT + base) = *(const uint4*)&bS[0];
        *(uint4*)(ksT + base + 8) = *(const uint4*)&bS[8];
        *(uint4*)(vT + base) = *(const uint4*)&bV[0];
        *(uint4*)(vT + base + 8) = *(const uint4*)&bV[8];
    }
    __syncthreads();
    // flux MLP: wave wv -> tokens wv*16..+15
    {
        const int wm_t = wv * 16;
        f32x4 fac[2] = {};
        #pragma unroll
        for (int kk = 0; kk < 2; ++kk) {
            bf16x8 af = *(const bf16x8*)&kbt[wm_t + ml][kk * 32 + q * 8];
            #pragma unroll
            for (int n = 0; n < 2; ++n) {
                bf16x8 bf = *(const bf16x8*)&wtf[n * 16 + ml][kk * 32 + q * 8];
                fac[n] = __builtin_amdgcn_mfma_f32_16x16x32_bf16(af, bf, fac[n], 0, 0, 0);
            }
        }
        const float bt2 = btf2[0];
        #pragma unroll
        for (int r = 0; r < 4; ++r) {
            float v = 0.f;
            #pragma unroll
            for (int n = 0; n < 2; ++n) {
                const int col = n * 16 + ml;
                const float hm = fac[n][r] + b1s[col];
                v += (hm / (1.f + expf(-hm))) * w2s[col];
            }
            v += __shfl_xor(v, 1, 64);
            v += __shfl_xor(v, 2, 64);
            v += __shfl_xor(v, 4, 64);
            v += __shfl_xor(v, 8, 64);
            if (ml == 0) {
                float tf = 1.f / (1.f + expf(-(v + bt2)));
                tf = fminf(fmaxf(tf, 0.01f), 0.99f);
                alphaA[(size_t)bh * L_ + l0 + wm_t + q * 4 + r] = 0.5f + 0.3f * tf;
            }
        }
    }
}

// ---------------------------------------------------------------------------
// M_fast/M_slow via MFMA; fp32 atomicAdd epilogue.
// ---------------------------------------------------------------------------
__global__ __launch_bounds__(256) void mstate_mfma_kernel(
    const unsigned short* __restrict__ kfT, const unsigned short* __restrict__ ksT,
    const unsigned short* __restrict__ vT,
    float* __restrict__ Mf, float* __restrict__ Ms)
{
    __shared__ unsigned short kf_s[64 * 32];
    __shared__ unsigned short ks_s[64 * 32];
    __shared__ unsigned short v_s[64 * 32];
    const int bh = blockIdx.x;
    const int seg = blockIdx.y;
    const int t = threadIdx.x, wv = t >> 6, lane = t & 63;
    const int q = lane >> 4, ml = lane & 15;
    const int wm = (wv >> 1) * 32, wn = (wv & 1) * 32;
    const size_t hb = (size_t)bh * DK_ * L_;
    const size_t grow = hb + (size_t)(wv * 16 + (lane >> 2)) * L_ + (lane & 3) * 8;
    f32x4 aF[2][2] = {}, aS[2][2] = {};
    for (int l0 = seg * 256; l0 < seg * 256 + 256; l0 += 32) {
        __syncthreads();
        gl_lds16(kfT + grow + l0, &kf_s[wv * 512]);
        gl_lds16(ksT + grow + l0, &ks_s[wv * 512]);
        gl_lds16(vT  + grow + l0, &v_s[wv * 512]);
        __syncthreads();
        bf16x8 fa[2], sa[2], vb[2];
        #pragma unroll
        for (int i = 0; i < 2; ++i) {
            fa[i] = *(const bf16x8*)&kf_s[(wm + i * 16 + ml) * 32 + q * 8];
            sa[i] = *(const bf16x8*)&ks_s[(wm + i * 16 + ml) * 32 + q * 8];
            vb[i] = *(const bf16x8*)&v_s[(wn + i * 16 + ml) * 32 + q * 8];
        }
        #pragma unroll
        for (int i = 0; i < 2; ++i)
            #pragma unroll
            for (int j = 0; j < 2; ++j) {
                aF[i][j] = __builtin_amdgcn_mfma_f32_16x16x32_bf16(fa[i], vb[j], aF[i][j], 0, 0, 0);
                aS[i][j] = __builtin_amdgcn_mfma_f32_16x16x32_bf16(sa[i], vb[j], aS[i][j], 0, 0, 0);
            }
    }
    #pragma unroll
    for (int i = 0; i < 2; ++i)
        #pragma unroll
        for (int j = 0; j < 2; ++j)
            #pragma unroll
            for (int r = 0; r < 4; ++r) {
                const int d = wm + i * 16 + q * 4 + r;
                const int e = wn + j * 16 + ml;
                atomicAdd(&Mf[(size_t)bh * (DK_ * DK_) + d * DK_ + e], aF[i][j][r]);
                atomicAdd(&Ms[(size_t)bh * (DK_ * DK_) + d * DK_ + e], aS[i][j][r]);
            }
}

// ---------------------------------------------------------------------------
// MtFS[bh][128][64] bf16: rows 0-63 = (Mf/dF)^T, 64-127 = (Ms/dS)^T
// ---------------------------------------------------------------------------
__global__ __launch_bounds__(256) void mprep_kernel(
    const float* __restrict__ Mf, const float* __restrict__ Ms,
    const float* __restrict__ denom, unsigned short* __restrict__ MtFS)
{
    __shared__ float mt[64][65];
    const int bh = blockIdx.x;
    const int t = threadIdx.x;
    const int r = t >> 2, c0 = (t & 3) * 16;
    #pragma unroll
    for (int s = 0; s < 2; ++s) {
        const float* M = (s == 0 ? Mf : Ms) + (size_t)bh * (DK_ * DK_);
        const float dn = denom[bh * 2 + s];
        __syncthreads();
        #pragma unroll
        for (int u = 0; u < 4; ++u) {
            float4 v = *(const float4*)&M[r * DK_ + c0 + u * 4];
            mt[r][c0 + u * 4 + 0] = v.x; mt[r][c0 + u * 4 + 1] = v.y;
            mt[r][c0 + u * 4 + 2] = v.z; mt[r][c0 + u * 4 + 3] = v.w;
        }
        __syncthreads();
        __align__(16) unsigned short ob[16];
        #pragma unroll
        for (int j = 0; j < 16; ++j) ob[j] = f2bf(mt[c0 + j][r] / dn);
        unsigned short* dst = MtFS + ((size_t)bh * 128 + s * 64 + r) * 64 + c0;
        *(uint4*)dst = *(const uint4*)&ob[0];
        *(uint4*)(dst + 8) = *(const uint4*)&ob[8];
    }
}

// ---------------------------------------------------------------------------
// o via MFMA: 128 tokens x 64 e per block; raw q from QKVb; q-norm folded into
// epilogue ((q/||q||)@M = (q@M)/||q||); alpha-mix; bf16 out.
// ---------------------------------------------------------------------------
__global__ __launch_bounds__(256) void o_mfma_kernel(
    const unsigned short* __restrict__ QKVb, const unsigned short* __restrict__ MtFS,
    const float* __restrict__ alphaA, unsigned short* __restrict__ Ob)
{
    __shared__ unsigned short As[128 * 72];   // raw q tile
    __shared__ unsigned short Bs[128 * 72];   // MtFS tile
    __shared__ float al[128];
    __shared__ float qs2[128][2];
    __shared__ float nrm[128];
    const int bh = blockIdx.x, lb = blockIdx.y;
    const int b = bh >> 4, h = bh & 15;
    const int t = threadIdx.x, wv = t >> 6, lane = t & 63;
    const int q = lane >> 4, ml = lane & 15;
    const int l0 = lb * 128;
    const int r0 = b * L_ + l0;
    #pragma unroll
    for (int c = 0; c < 4; ++c) {
        const int id = t + c * 256;
        const int row = id >> 3, ko = (id & 7) * 8;
        *(uint4*)&As[row * 72 + ko] =
            *(const uint4*)(QKVb + (size_t)(r0 + row) * N3_ + h * DK_ + ko);
        *(uint4*)&Bs[row * 72 + ko] =
            *(const uint4*)(MtFS + ((size_t)bh * 128 + row) * 64 + ko);
    }
    if (t < 128) al[t] = alphaA[(size_t)bh * L_ + l0 + t];
    __syncthreads();
    {
        const int row = t >> 1, half = (t & 1) * 32;
        float s = 0.f;
        #pragma unroll
        for (int j = 0; j < 32; ++j) {
            const float v = bf2f(As[row * 72 + half + j]);
            s += v * v;
        }
        qs2[row][t & 1] = s;
    }
    const int wm = wv * 32;
    f32x4 acc[2][2][4] = {};   // [state][m][n]
    #pragma unroll
    for (int kk = 0; kk < 2; ++kk) {
        bf16x8 af[2];
        #pragma unroll
        for (int m = 0; m < 2; ++m)
            af[m] = *(const bf16x8*)&As[(wm + m * 16 + ml) * 72 + kk * 32 + q * 8];
        #pragma unroll
        for (int s = 0; s < 2; ++s)
            #pragma unroll
            for (int n = 0; n < 4; ++n) {
                bf16x8 bf = *(const bf16x8*)&Bs[(s * 64 + n * 16 + ml) * 72 + kk * 32 + q * 8];
                #pragma unroll
                for (int m = 0; m < 2; ++m)
                    acc[s][m][n] = __builtin_amdgcn_mfma_f32_16x16x32_bf16(af[m], bf, acc[s][m][n], 0, 0, 0);
            }
    }
    __syncthreads();
    if (t < 128) nrm[t] = 1.f / fmaxf(sqrtf(qs2[t][0] + qs2[t][1]), 1e-12f);
    __syncthreads();
    unsigned short* Cs = Bs;
    #pragma unroll
    for (int m = 0; m < 2; ++m)
        #pragma unroll
        for (int r = 0; r < 4; ++r) {
            const int row = wm + m * 16 + q * 4 + r;
            const float a = al[row], sc = nrm[row];
            #pragma unroll
            for (int n = 0; n < 4; ++n) {
                const float v = sc * (a * acc[0][m][n][r] + (1.f - a) * acc[1][m][n][r]);
                Cs[row * 64 + n * 16 + ml] = f2bf(v);
            }
        }
    __syncthreads();
    const int row = t >> 1, eo = (t & 1) * 32;
    const uint4* src = (const uint4*)&Cs[row * 64 + eo];
    uint4* dst = (uint4*)(Ob + (size_t)(r0 + row) * D_ + h * DK_ + eo);
    #pragma unroll
    for (int u = 0; u < 4; ++u) dst[u] = src[u];
}

extern "C" void kernel_launch(void* const* d_in, const int* in_sizes, int n_in,
                              void* d_out, int out_size, void* d_ws, size_t ws_size,
                              hipStream_t stream)
{
    const float* x    = (const float*)d_in[0];
    const float* Wq   = (const float*)d_in[1];
    const float* Wk   = (const float*)d_in[2];
    const float* Wv   = (const float*)d_in[3];
    const float* Wb   = (const float*)d_in[4];
    const float* Wo   = (const float*)d_in[5];
    const float* Wfd  = (const float*)d_in[6];
    const float* bfd  = (const float*)d_in[7];
    const float* Wsd  = (const float*)d_in[8];
    const float* bsd  = (const float*)d_in[9];
    const float* Wtf1 = (const float*)d_in[10];
    const float* btf1 = (const float*)d_in[11];
    const float* Wtf2 = (const float*)d_in[12];
    const float* btf2 = (const float*)d_in[13];
    float* out        = (float*)d_out;

    char* w = (char*)d_ws;
    unsigned short* xb    = (unsigned short*)w; w += (size_t)R_ * D_ * 2;   // reused as Ob
    unsigned short* QKVb  = (unsigned short*)w; w += (size_t)R_ * N3_ * 2;
    unsigned short* Wtqkv = (unsigned short*)w; w += (size_t)3 * D_ * D_ * 2;
    unsigned short* Wto   = (unsigned short*)w; w += (size_t)D_ * D_ * 2;
    unsigned short* kfT   = (unsigned short*)w; w += (size_t)32 * DK_ * L_ * 2;
    unsigned short* ksT   = (unsigned short*)w; w += (size_t)32 * DK_ * L_ * 2;
    unsigned short* vT    = (unsigned short*)w; w += (size_t)32 * DK_ * L_ * 2;
    unsigned short* W3t   = (unsigned short*)w; w += (size_t)48 * D_ * 2;
    unsigned short* Wtf1t = (unsigned short*)w; w += (size_t)32 * DK_ * 2;
    unsigned short* MtFS  = (unsigned short*)w; w += (size_t)32 * 128 * DK_ * 2;
    float* beta   = (float*)w; w += 32 * L_ * 4;
    float* fastd  = (float*)w; w += 32 * L_ * 4;
    float* slowd  = (float*)w; w += 32 * L_ * 4;
    float* fw     = (float*)w; w += 32 * L_ * 4;
    float* sw     = (float*)w; w += 32 * L_ * 4;
    float* alphaA = (float*)w; w += 32 * L_ * 4;
    float* Mf     = (float*)w; w += 32 * DK_ * DK_ * 4;
    float* Ms     = (float*)w; w += 32 * DK_ * DK_ * 4;
    float* denom  = (float*)w; w += 64 * 4;

    // all prep in one dispatch
    prep_all_kernel<<<8192 + 4096 + 192 + 1, 256, 0, stream>>>(
        x, Wq, Wk, Wv, Wo, Wb, Wfd, Wsd, Wtf1, xb, Wtqkv, Wto, W3t, Wtf1t);

    // small projections + scan
    proj_mfma_kernel<<<R_ / 64, 256, 0, stream>>>(xb, W3t, bfd, bsd, beta, fastd, slowd);
    scan_kernel<<<64, 256, 0, stream>>>(fastd, slowd, fw, sw, denom);

    // fused QKV projection (bf16 out, coalesced epilogue)
    gemm_bf16_kernel<true><<<dim3(N3_ / 128, R_ / 128), 256, 0, stream>>>(
        xb, Wtqkv, QKVb, R_, N3_, D_);

    ktv_flux_kernel<<<dim3(H_, B_, L_ / 64), 256, 0, stream>>>(
        QKVb, beta, fw, sw, Wtf1t, btf1, Wtf2, btf2, kfT, ksT, vT, alphaA);
    (void)hipMemsetAsync(Mf, 0, 2 * 32 * DK_ * DK_ * sizeof(float), stream);
    mstate_mfma_kernel<<<dim3(32, 16), 256, 0, stream>>>(kfT, ksT, vT, Mf, Ms);
    mprep_kernel<<<32, 256, 0, stream>>>(Mf, Ms, denom, MtFS);
    o_mfma_kernel<<<dim3(32, 32), 256, 0, stream>>>(QKVb, MtFS, alphaA, xb);
    gemm_bf16_kernel<false><<<dim3(D_ / 128, R_ / 128), 256, 0, stream>>>(
        xb, Wto, out, R_, D_, D_);
}